// Round 2
// baseline (301.202 us; speedup 1.0000x reference)
//
#include <hip/hip_runtime.h>
#include <hip/hip_cooperative_groups.h>
#include <math.h>

namespace cg = cooperative_groups;

#define EMBED 256
#define HEADS 8
#define PDIM  32
#define BATCH 2
#define SEQ   1728            // 12*12*12
#define NTOK  (BATCH*SEQ)     // 3456
#define NE    (NTOK*EMBED)    // 884736
#define NKT   (SEQ/64)        // 27 key tiles
#define WSZ   (EMBED*EMBED)   // 65536
#define XCH   (NE/8)          // 110592 x-chunks
#define WCH   (WSZ/8)         // 8192 W-chunks (power of 2)
#define NBLK  432
#define NTHR  256
#define TOTTHR  (NBLK*NTHR)   // 110592 threads
#define TOTWAVE (TOTTHR/64)   // 1728 waves
#define QKV_UNITS 2592        // 108 m-tiles * 8 n-tiles * 3 z
#define LOG2E 1.44269504088896f

typedef __attribute__((ext_vector_type(8))) __bf16 bf16x8;
typedef __attribute__((ext_vector_type(4))) float  f32x4;
typedef unsigned short ushort_t;
typedef unsigned int   uint_t;

static __device__ __forceinline__ unsigned short f2bf_rne(float f) {
    union { float f; unsigned u; } x; x.f = f;
    unsigned r = x.u + 0x7fffu + ((x.u >> 16) & 1u);
    return (unsigned short)(r >> 16);
}
union v8cast { uint4 u; bf16x8 v; };

// split 8 floats into bf16 hi (round-half-up) + bf16 lo residual, packed
static __device__ __forceinline__ void cvt8_hilo(const float f[8], bf16x8& hi, bf16x8& lo) {
    uint4 ph, pl;
    uint_t* phv = (uint_t*)&ph; uint_t* plv = (uint_t*)&pl;
    #pragma unroll
    for (int j = 0; j < 4; ++j) {
        const float f0 = f[2 * j], f1 = f[2 * j + 1];
        const uint_t u0 = __float_as_uint(f0) + 0x8000u;
        const uint_t u1 = __float_as_uint(f1) + 0x8000u;
        phv[j] = __builtin_amdgcn_perm(u1, u0, 0x07060302u);
        const float l0 = f0 - __uint_as_float(u0 & 0xFFFF0000u);
        const float l1 = f1 - __uint_as_float(u1 & 0xFFFF0000u);
        plv[j] = __builtin_amdgcn_perm(__float_as_uint(l1) + 0x8000u,
                                       __float_as_uint(l0) + 0x8000u, 0x07060302u);
    }
    v8cast ch; ch.u = ph; hi = ch.v;
    v8cast cl; cl.u = pl; lo = cl.v;
}

struct AttnLds {
    ushort_t Ks[2][64][40];   // 10240 B
    ushort_t Vs[2][32][72];   //  9216 B
    ushort_t Ps[4][16][72];   //  9216 B  -> 28672 B total
};

// ---------------------------------------------------------------------------
// Phase 0: one-time conversions.  x -> xhi/xlo bf16 [tok][k];
// Wq/Wk/Wv -> transposed hi/lo bf16 [z][n][k]; Wo -> transposed hi bf16 [n][k].
// Grid-stride over XCH + 4*WCH = 143360 chunks (110592 threads).
// ---------------------------------------------------------------------------
static __device__ __forceinline__ void dev_prep(
    const float* __restrict__ x,
    const float* __restrict__ Wq, const float* __restrict__ Wk,
    const float* __restrict__ Wv, const float* __restrict__ Wo,
    ushort_t* __restrict__ xhi, ushort_t* __restrict__ xlo,
    ushort_t* __restrict__ wthi, ushort_t* __restrict__ wtlo,
    ushort_t* __restrict__ wot)
{
    const int tid = blockIdx.x * NTHR + threadIdx.x;
    for (int id = tid; id < XCH + 4 * WCH; id += TOTTHR) {
        if (id < XCH) {
            float f[8];
            *(float4*)&f[0] = *(const float4*)(x + (size_t)id * 8);
            *(float4*)&f[4] = *(const float4*)(x + (size_t)id * 8 + 4);
            bf16x8 hi, lo; cvt8_hilo(f, hi, lo);
            v8cast ch; ch.v = hi; *(uint4*)&xhi[(size_t)id * 8] = ch.u;
            v8cast cl; cl.v = lo; *(uint4*)&xlo[(size_t)id * 8] = cl.u;
        } else if (id < XCH + 3 * WCH) {
            int r = id - XCH;
            const int z = r >> 13; r &= (WCH - 1);
            const float* __restrict__ W = (z == 0) ? Wq : (z == 1) ? Wk : Wv;
            const int n = r >> 5, kc = (r & 31) * 8;
            float f[8];
            #pragma unroll
            for (int j = 0; j < 8; ++j) f[j] = W[(size_t)(kc + j) * EMBED + n];
            bf16x8 hi, lo; cvt8_hilo(f, hi, lo);
            v8cast ch; ch.v = hi; *(uint4*)&wthi[(size_t)z * WSZ + n * EMBED + kc] = ch.u;
            v8cast cl; cl.v = lo; *(uint4*)&wtlo[(size_t)z * WSZ + n * EMBED + kc] = cl.u;
        } else {
            int r = id - XCH - 3 * WCH;
            const int n = r >> 5, kc = (r & 31) * 8;
            float f[8];
            #pragma unroll
            for (int j = 0; j < 8; ++j) f[j] = Wo[(size_t)(kc + j) * EMBED + n];
            bf16x8 hi, lo; cvt8_hilo(f, hi, lo);
            v8cast ch; ch.v = hi; *(uint4*)&wot[n * EMBED + kc] = ch.u;
        }
    }
}

// ---------------------------------------------------------------------------
// Phase 1: QKV projection, pure-bf16 MFMA.  Wave tile 32(M) x 32(N), K=256,
// 3-term hi/lo product.  2592 units wave-strided over 1728 waves.
// Q,K -> [b][h][s][p];  V -> [b][h][p][s] (transposed).
// ---------------------------------------------------------------------------
static __device__ __forceinline__ void dev_qkv(
    const ushort_t* __restrict__ xhi, const ushort_t* __restrict__ xlo,
    const ushort_t* __restrict__ wthi, const ushort_t* __restrict__ wtlo,
    const float* __restrict__ bq, const float* __restrict__ bk, const float* __restrict__ bv,
    ushort_t* __restrict__ qo, ushort_t* __restrict__ ko, ushort_t* __restrict__ vt)
{
    const int lane = threadIdx.x & 63, li = lane & 15, quad = lane >> 4;
    const int gw = blockIdx.x * (NTHR / 64) + (threadIdx.x >> 6);
    for (int u = gw; u < QKV_UNITS; u += TOTWAVE) {
        const int z   = u / 864;
        const int rem = u - z * 864;
        const int nb  = rem / 108;
        const int mb  = rem - nb * 108;
        const int m0 = mb * 32, n0 = nb * 32;
        const float* __restrict__ bias = (z == 0) ? bq : (z == 1) ? bk : bv;

        const ushort_t* ahp = xhi + (size_t)(m0 + li) * EMBED + quad * 8;
        const ushort_t* alp = xlo + (size_t)(m0 + li) * EMBED + quad * 8;
        const ushort_t* bhp = wthi + (size_t)z * WSZ + (size_t)(n0 + li) * EMBED + quad * 8;
        const ushort_t* blp = wtlo + (size_t)z * WSZ + (size_t)(n0 + li) * EMBED + quad * 8;

        f32x4 acc[2][2];
        #pragma unroll
        for (int mt = 0; mt < 2; ++mt)
            #pragma unroll
            for (int nt = 0; nt < 2; ++nt)
                acc[mt][nt] = (f32x4){0.f, 0.f, 0.f, 0.f};

        #pragma unroll 2
        for (int k0 = 0; k0 < EMBED; k0 += 32) {
            bf16x8 ah[2], al[2], bh[2], bl[2];
            #pragma unroll
            for (int mt = 0; mt < 2; ++mt) {
                ah[mt] = *(const bf16x8*)(ahp + (size_t)mt * 16 * EMBED + k0);
                al[mt] = *(const bf16x8*)(alp + (size_t)mt * 16 * EMBED + k0);
            }
            #pragma unroll
            for (int nt = 0; nt < 2; ++nt) {
                bh[nt] = *(const bf16x8*)(bhp + (size_t)nt * 16 * EMBED + k0);
                bl[nt] = *(const bf16x8*)(blp + (size_t)nt * 16 * EMBED + k0);
            }
            #pragma unroll
            for (int mt = 0; mt < 2; ++mt)
                #pragma unroll
                for (int nt = 0; nt < 2; ++nt) {
                    acc[mt][nt] = __builtin_amdgcn_mfma_f32_16x16x32_bf16(ah[mt], bh[nt], acc[mt][nt], 0, 0, 0);
                    acc[mt][nt] = __builtin_amdgcn_mfma_f32_16x16x32_bf16(al[mt], bh[nt], acc[mt][nt], 0, 0, 0);
                    acc[mt][nt] = __builtin_amdgcn_mfma_f32_16x16x32_bf16(ah[mt], bl[nt], acc[mt][nt], 0, 0, 0);
                }
        }

        const int b = m0 / SEQ;          // 32-row tile never straddles batch
        const int sbase = m0 - b * SEQ;

        if (z <= 1) {
            ushort_t* __restrict__ dst = z ? ko : qo;
            #pragma unroll
            for (int nt = 0; nt < 2; ++nt) {
                const int gcol = n0 + nt * 16 + li;
                const int h = gcol >> 5, p = gcol & 31;
                const float bb = bias[gcol];
                ushort_t* base = dst + ((size_t)(b * HEADS + h) * SEQ) * PDIM + p;
                #pragma unroll
                for (int mt = 0; mt < 2; ++mt)
                    #pragma unroll
                    for (int r = 0; r < 4; ++r) {
                        const int s = sbase + mt * 16 + quad * 4 + r;
                        base[(size_t)s * PDIM] = f2bf_rne(acc[mt][nt][r] + bb);
                    }
            }
        } else {
            #pragma unroll
            for (int nt = 0; nt < 2; ++nt) {
                const int gcol = n0 + nt * 16 + li;
                const int h = gcol >> 5, p = gcol & 31;
                const float bb = bias[gcol];
                ushort_t* base = vt + ((size_t)(b * HEADS + h) * PDIM + p) * SEQ;
                #pragma unroll
                for (int mt = 0; mt < 2; ++mt) {
                    const int s0 = sbase + mt * 16 + quad * 4;
                    ushort4 w;
                    w.x = f2bf_rne(acc[mt][nt][0] + bb);
                    w.y = f2bf_rne(acc[mt][nt][1] + bb);
                    w.z = f2bf_rne(acc[mt][nt][2] + bb);
                    w.w = f2bf_rne(acc[mt][nt][3] + bb);
                    *(ushort4*)&base[s0] = w;
                }
            }
        }
    }
}

// ---------------------------------------------------------------------------
// Phase 2: flash attention (round-0 verified structure).  1 unit per block:
// 4 waves x 16 q-rows = 64 rows; 27 key tiles double-buffered in LDS,
// one barrier per tile.  Output bf16 [b][s][h][p].
// ---------------------------------------------------------------------------
static __device__ __forceinline__ void dev_attn(
    AttnLds& S,
    const ushort_t* __restrict__ q, const ushort_t* __restrict__ k,
    const ushort_t* __restrict__ vt, ushort_t* __restrict__ aob)
{
    const int t    = threadIdx.x;
    const int lane = t & 63;
    const int w    = t >> 6;
    const int li   = lane & 15;
    const int quad = lane >> 4;
    const int bid  = blockIdx.x;
    const int qt   = bid % 27;
    const int bh   = bid / 27;
    const int b  = bh >> 3, h = bh & 7;
    const int q0 = qt * 64 + w * 16;

    const ushort_t* __restrict__ qb = q  + (size_t)bh * SEQ * PDIM;
    const ushort_t* __restrict__ kb = k  + (size_t)bh * SEQ * PDIM;
    const ushort_t* __restrict__ vb = vt + (size_t)bh * PDIM * SEQ;

    const bf16x8 qfrag = *(const bf16x8*)(qb + (size_t)(q0 + li) * PDIM + quad * 8);

    // staging assignment (per lane): K row jk, 8-col chunk ck; V row pv, chunk cv
    const int jk = w * 16 + (lane >> 2), ck = (lane & 3) * 8;
    const int pv = w * 8 + (lane >> 3),  cv = (lane & 7) * 8;
    const ushort_t* kgp = kb + (size_t)jk * PDIM + ck;
    const ushort_t* vgp = vb + (size_t)pv * SEQ + cv;

    f32x4 o0 = {0.f, 0.f, 0.f, 0.f};
    f32x4 o1 = {0.f, 0.f, 0.f, 0.f};
    float m_run = -__builtin_inff(), l_run = 0.f;

    uint4 kreg = *(const uint4*)(kgp);
    uint4 vreg = *(const uint4*)(vgp);

    for (int kt = 0; kt < NKT; ++kt) {
        const int p = kt & 1;
        *(uint4*)&S.Ks[p][jk][ck] = kreg;
        *(uint4*)&S.Vs[p][pv][cv] = vreg;
        __syncthreads();
        if (kt + 1 < NKT) {
            kreg = *(const uint4*)(kgp + (size_t)(kt + 1) * 64 * PDIM);
            vreg = *(const uint4*)(vgp + (kt + 1) * 64);
        }

        // ---- S^T = K * Q^T ----
        const f32x4 zero = {0.f, 0.f, 0.f, 0.f};
        f32x4 st[4];
        #pragma unroll
        for (int jt = 0; jt < 4; ++jt) {
            const bf16x8 kf = *(const bf16x8*)&S.Ks[p][jt * 16 + li][quad * 8];
            st[jt] = __builtin_amdgcn_mfma_f32_16x16x32_bf16(kf, qfrag, zero, 0, 0, 0);
        }

        // ---- online softmax (per-lane stats for query col i=li) ----
        float tm = st[0][0];
        #pragma unroll
        for (int jt = 0; jt < 4; ++jt)
            #pragma unroll
            for (int r = 0; r < 4; ++r) tm = fmaxf(tm, st[jt][r]);
        tm = fmaxf(tm, __shfl_xor(tm, 16));
        tm = fmaxf(tm, __shfl_xor(tm, 32));
        const float mnew  = fmaxf(m_run, tm);
        const float negml = -(mnew * LOG2E);

        float ps = 0.f;
        #pragma unroll
        for (int jt = 0; jt < 4; ++jt) {
            const float p0 = __builtin_amdgcn_exp2f(fmaf(st[jt][0], LOG2E, negml));
            const float p1 = __builtin_amdgcn_exp2f(fmaf(st[jt][1], LOG2E, negml));
            const float p2 = __builtin_amdgcn_exp2f(fmaf(st[jt][2], LOG2E, negml));
            const float p3 = __builtin_amdgcn_exp2f(fmaf(st[jt][3], LOG2E, negml));
            ps += (p0 + p1) + (p2 + p3);
            uint2 pw;
            pw.x = __builtin_amdgcn_perm(__float_as_uint(p1) + 0x8000u,
                                         __float_as_uint(p0) + 0x8000u, 0x07060302u);
            pw.y = __builtin_amdgcn_perm(__float_as_uint(p3) + 0x8000u,
                                         __float_as_uint(p2) + 0x8000u, 0x07060302u);
            *(uint2*)&S.Ps[w][li][16 * jt + 4 * quad] = pw;
        }
        ps += __shfl_xor(ps, 16);
        ps += __shfl_xor(ps, 32);

        const float alpha = __builtin_amdgcn_exp2f(fmaf(m_run, LOG2E, negml));
        l_run = fmaf(l_run, alpha, ps);
        m_run = mnew;

        float af[4];
        #pragma unroll
        for (int r = 0; r < 4; ++r) af[r] = __shfl(alpha, 4 * quad + r);
        #pragma unroll
        for (int r = 0; r < 4; ++r) { o0[r] *= af[r]; o1[r] *= af[r]; }

        // ---- O += P * V ----
        const bf16x8 pa0 = *(const bf16x8*)&S.Ps[w][li][8 * quad];
        const bf16x8 pa1 = *(const bf16x8*)&S.Ps[w][li][32 + 8 * quad];
        const bf16x8 vf00 = *(const bf16x8*)&S.Vs[p][li][quad * 8];
        const bf16x8 vf01 = *(const bf16x8*)&S.Vs[p][16 + li][quad * 8];
        const bf16x8 vf10 = *(const bf16x8*)&S.Vs[p][li][32 + quad * 8];
        const bf16x8 vf11 = *(const bf16x8*)&S.Vs[p][16 + li][32 + quad * 8];
        o0 = __builtin_amdgcn_mfma_f32_16x16x32_bf16(pa0, vf00, o0, 0, 0, 0);
        o0 = __builtin_amdgcn_mfma_f32_16x16x32_bf16(pa1, vf10, o0, 0, 0, 0);
        o1 = __builtin_amdgcn_mfma_f32_16x16x32_bf16(pa0, vf01, o1, 0, 0, 0);
        o1 = __builtin_amdgcn_mfma_f32_16x16x32_bf16(pa1, vf11, o1, 0, 0, 0);
    }

    // ---- epilogue: divide by l, write bf16 [b][s][h][p] ----
    float linv[4];
    #pragma unroll
    for (int r = 0; r < 4; ++r) linv[r] = 1.0f / __shfl(l_run, 4 * quad + r);
    #pragma unroll
    for (int r = 0; r < 4; ++r) {
        const int s = q0 + 4 * quad + r;
        ushort_t* row = aob + ((size_t)(b * SEQ + s)) * EMBED + h * PDIM;
        row[li]      = f2bf_rne(o0[r] * linv[r]);
        row[16 + li] = f2bf_rne(o1[r] * linv[r]);
    }
}

// ---------------------------------------------------------------------------
// Phase 3: output projection, bf16 MFMA.  Wave tile 32(M) x 16(N), K=256.
// Exactly 1728 units = 1 per wave.  out fp32.
// ---------------------------------------------------------------------------
static __device__ __forceinline__ void dev_out(
    const ushort_t* __restrict__ a, const ushort_t* __restrict__ wot,
    const float* __restrict__ bo, float* __restrict__ out)
{
    const int lane = threadIdx.x & 63, li = lane & 15, quad = lane >> 4;
    const int gw = blockIdx.x * (NTHR / 64) + (threadIdx.x >> 6);
    const int nb = gw / 108, mb = gw - nb * 108;
    const int m0 = mb * 32, n0 = nb * 16;

    const ushort_t* ap = a + (size_t)(m0 + li) * EMBED + quad * 8;
    const ushort_t* bp = wot + (size_t)(n0 + li) * EMBED + quad * 8;

    f32x4 acc[2];
    #pragma unroll
    for (int mt = 0; mt < 2; ++mt) acc[mt] = (f32x4){0.f, 0.f, 0.f, 0.f};

    #pragma unroll 2
    for (int k0 = 0; k0 < EMBED; k0 += 32) {
        bf16x8 ah[2];
        #pragma unroll
        for (int mt = 0; mt < 2; ++mt)
            ah[mt] = *(const bf16x8*)(ap + (size_t)mt * 16 * EMBED + k0);
        const bf16x8 bf = *(const bf16x8*)(bp + k0);
        #pragma unroll
        for (int mt = 0; mt < 2; ++mt)
            acc[mt] = __builtin_amdgcn_mfma_f32_16x16x32_bf16(ah[mt], bf, acc[mt], 0, 0, 0);
    }

    const float bb = bo[n0 + li];
    #pragma unroll
    for (int mt = 0; mt < 2; ++mt)
        #pragma unroll
        for (int r = 0; r < 4; ++r) {
            const int row = m0 + mt * 16 + quad * 4 + r;
            out[(size_t)row * EMBED + n0 + li] = acc[mt][r] + bb;
        }
}

// ---------------------------------------------------------------------------
// Fused cooperative kernel: all 4 phases, 3 grid syncs, 1 launch.
// grid 432 x 256.  Co-residency: LDS 28672 B + VGPR<=256 (launch_bounds 256,2)
// -> >=2 blocks/CU -> capacity >=512 blocks >= 432.
// ---------------------------------------------------------------------------
__global__ __launch_bounds__(256, 2) void fused_kernel(
    const float* __restrict__ x,
    const float* __restrict__ Wq, const float* __restrict__ bq,
    const float* __restrict__ Wk, const float* __restrict__ bk,
    const float* __restrict__ Wv, const float* __restrict__ bv,
    const float* __restrict__ Wo, const float* __restrict__ bo,
    float* __restrict__ out,
    ushort_t* __restrict__ qb, ushort_t* __restrict__ kb,
    ushort_t* __restrict__ vtb, ushort_t* __restrict__ aob,
    ushort_t* __restrict__ xhi, ushort_t* __restrict__ xlo,
    ushort_t* __restrict__ wthi, ushort_t* __restrict__ wtlo,
    ushort_t* __restrict__ wot)
{
    __shared__ AttnLds S;
    dev_prep(x, Wq, Wk, Wv, Wo, xhi, xlo, wthi, wtlo, wot);
    cg::this_grid().sync();
    dev_qkv(xhi, xlo, wthi, wtlo, bq, bk, bv, qb, kb, vtb);
    cg::this_grid().sync();
    dev_attn(S, qb, kb, vtb, aob);
    cg::this_grid().sync();
    dev_out(aob, wot, bo, out);
}

// --------- fallback wrappers (same grid shape), used only if coop fails -----
__global__ __launch_bounds__(256, 2) void prep_k(
    const float* __restrict__ x, const float* __restrict__ Wq,
    const float* __restrict__ Wk, const float* __restrict__ Wv,
    const float* __restrict__ Wo, ushort_t* __restrict__ xhi,
    ushort_t* __restrict__ xlo, ushort_t* __restrict__ wthi,
    ushort_t* __restrict__ wtlo, ushort_t* __restrict__ wot)
{ dev_prep(x, Wq, Wk, Wv, Wo, xhi, xlo, wthi, wtlo, wot); }

__global__ __launch_bounds__(256, 2) void qkv_k(
    const ushort_t* __restrict__ xhi, const ushort_t* __restrict__ xlo,
    const ushort_t* __restrict__ wthi, const ushort_t* __restrict__ wtlo,
    const float* __restrict__ bq, const float* __restrict__ bk,
    const float* __restrict__ bv, ushort_t* __restrict__ qo,
    ushort_t* __restrict__ ko, ushort_t* __restrict__ vt)
{ dev_qkv(xhi, xlo, wthi, wtlo, bq, bk, bv, qo, ko, vt); }

__global__ __launch_bounds__(256, 2) void attn_k(
    const ushort_t* __restrict__ q, const ushort_t* __restrict__ k,
    const ushort_t* __restrict__ vt, ushort_t* __restrict__ aob)
{ __shared__ AttnLds S; dev_attn(S, q, k, vt, aob); }

__global__ __launch_bounds__(256, 2) void out_k(
    const ushort_t* __restrict__ a, const ushort_t* __restrict__ wot,
    const float* __restrict__ bo, float* __restrict__ out)
{ dev_out(a, wot, bo, out); }

// ---------------------------------------------------------------------------
extern "C" void kernel_launch(void* const* d_in, const int* in_sizes, int n_in,
                              void* d_out, int out_size, void* d_ws, size_t ws_size,
                              hipStream_t stream)
{
    const float* x  = (const float*)d_in[0];
    const float* Wq = (const float*)d_in[1];
    const float* bq = (const float*)d_in[2];
    const float* Wk = (const float*)d_in[3];
    const float* bk = (const float*)d_in[4];
    const float* Wv = (const float*)d_in[5];
    const float* bv = (const float*)d_in[6];
    const float* Wo = (const float*)d_in[7];
    const float* bo = (const float*)d_in[8];
    float* out = (float*)d_out;

    ushort_t* ws   = (ushort_t*)d_ws;
    ushort_t* qb   = ws;                         // [b][h][s][p] bf16
    ushort_t* kb   = qb   + (size_t)NE;
    ushort_t* vtb  = kb   + (size_t)NE;          // [b][h][p][s] bf16
    ushort_t* aob  = vtb  + (size_t)NE;          // [b][s][h][p] bf16
    ushort_t* xhi  = aob  + (size_t)NE;          // [tok][k] bf16
    ushort_t* xlo  = xhi  + (size_t)NE;
    ushort_t* wthi = xlo  + (size_t)NE;          // [z][n][k] bf16
    ushort_t* wtlo = wthi + (size_t)(3 * WSZ);
    ushort_t* wot  = wtlo + (size_t)(3 * WSZ);   // [n][k] bf16

    void* args[] = {
        (void*)&x, (void*)&Wq, (void*)&bq, (void*)&Wk, (void*)&bk,
        (void*)&Wv, (void*)&bv, (void*)&Wo, (void*)&bo, (void*)&out,
        (void*)&qb, (void*)&kb, (void*)&vtb, (void*)&aob,
        (void*)&xhi, (void*)&xlo, (void*)&wthi, (void*)&wtlo, (void*)&wot
    };

    hipError_t err = hipLaunchCooperativeKernel(
        reinterpret_cast<void*>(fused_kernel),
        dim3(NBLK), dim3(NTHR), args, 0, stream);

    if (err != hipSuccess) {
        // cooperative launch not available here: clear error, fall back to
        // the 4-kernel pipeline (identical phase bodies, same grid shapes).
        (void)hipGetLastError();
        prep_k<<<dim3(NBLK), dim3(NTHR), 0, stream>>>(
            x, Wq, Wk, Wv, Wo, xhi, xlo, wthi, wtlo, wot);
        qkv_k<<<dim3(NBLK), dim3(NTHR), 0, stream>>>(
            xhi, xlo, wthi, wtlo, bq, bk, bv, qb, kb, vtb);
        attn_k<<<dim3(NBLK), dim3(NTHR), 0, stream>>>(qb, kb, vtb, aob);
        out_k<<<dim3(NBLK), dim3(NTHR), 0, stream>>>(aob, wot, bo, out);
    }
}

// Round 3
// 119.530 us; speedup vs baseline: 2.5199x; 2.5199x over previous
//
#include <hip/hip_runtime.h>
#include <math.h>

#define EMBED 256
#define HEADS 8
#define PDIM  32
#define BATCH 2
#define SEQ   1728            // 12*12*12
#define NTOK  (BATCH*SEQ)     // 3456
#define NE    (NTOK*EMBED)    // 884736
#define KVB   128             // keys per attn iteration (main loop)
#define NMAIN 13              // 13*128 = 1664 keys
#define TAIL0 1664            // tail: keys 1664..1727 (64 keys)
#define LOG2E 1.44269504088896f

typedef __attribute__((ext_vector_type(8))) __bf16 bf16x8;
typedef __attribute__((ext_vector_type(4))) float  f32x4;
typedef unsigned short ushort_t;
typedef unsigned int   uint_t;

static __device__ __forceinline__ unsigned short f2bf_rne(float f) {
    union { float f; unsigned u; } x; x.f = f;
    unsigned r = x.u + 0x7fffu + ((x.u >> 16) & 1u);
    return (unsigned short)(r >> 16);
}
union v8cast { uint4 u; bf16x8 v; };

// split 8 floats into bf16 hi (round-half-up) + bf16 lo residual, packed
static __device__ __forceinline__ void cvt8_hilo(const float f[8], bf16x8& hi, bf16x8& lo) {
    uint4 ph, pl;
    uint_t* phv = (uint_t*)&ph; uint_t* plv = (uint_t*)&pl;
    #pragma unroll
    for (int j = 0; j < 4; ++j) {
        const float f0 = f[2 * j], f1 = f[2 * j + 1];
        const uint_t u0 = __float_as_uint(f0) + 0x8000u;
        const uint_t u1 = __float_as_uint(f1) + 0x8000u;
        phv[j] = __builtin_amdgcn_perm(u1, u0, 0x07060302u);
        const float l0 = f0 - __uint_as_float(u0 & 0xFFFF0000u);
        const float l1 = f1 - __uint_as_float(u1 & 0xFFFF0000u);
        plv[j] = __builtin_amdgcn_perm(__float_as_uint(l1) + 0x8000u,
                                       __float_as_uint(l0) + 0x8000u, 0x07060302u);
    }
    v8cast ch; ch.u = ph; hi = ch.v;
    v8cast cl; cl.u = pl; lo = cl.v;
}

// ---------------------------------------------------------------------------
// Kernel 1: QKV projection, fused fp32->bf16 hi/lo conversion + MFMA.
// grid (54, 8, 3) x 64 (1 wave).  Wave tile 64(M) x 32(N), K=256.
// (verbatim from the 119.9 us build)
// ---------------------------------------------------------------------------
__global__ __launch_bounds__(64) void qkv_gemm_kernel(
    const float* __restrict__ x,
    const float* __restrict__ Wq, const float* __restrict__ bq,
    const float* __restrict__ Wk, const float* __restrict__ bk,
    const float* __restrict__ Wv, const float* __restrict__ bv,
    ushort_t* __restrict__ qo, ushort_t* __restrict__ ko, ushort_t* __restrict__ vt)
{
    const int lane = threadIdx.x, li = lane & 15, quad = lane >> 4;
    const int m0 = blockIdx.x * 64, n0 = blockIdx.y * 32, z = blockIdx.z;
    const float* __restrict__ W    = (z == 0) ? Wq : (z == 1) ? Wk : Wv;
    const float* __restrict__ bias = (z == 0) ? bq : (z == 1) ? bk : bv;

    const float* ap = x + (size_t)(m0 + li) * EMBED + quad * 8;

    f32x4 acc[4][2];
    #pragma unroll
    for (int mt = 0; mt < 4; ++mt)
        #pragma unroll
        for (int nt = 0; nt < 2; ++nt)
            acc[mt][nt] = (f32x4){0.f, 0.f, 0.f, 0.f};

    #pragma unroll 2
    for (int k0 = 0; k0 < EMBED; k0 += 32) {
        bf16x8 ah[4], al[4];
        #pragma unroll
        for (int mt = 0; mt < 4; ++mt) {
            float af[8];
            *(float4*)&af[0] = *(const float4*)(ap + (size_t)mt * 16 * EMBED + k0);
            *(float4*)&af[4] = *(const float4*)(ap + (size_t)mt * 16 * EMBED + k0 + 4);
            cvt8_hilo(af, ah[mt], al[mt]);
        }
        bf16x8 bh[2], bl[2];
        #pragma unroll
        for (int nt = 0; nt < 2; ++nt) {
            const int n = n0 + nt * 16 + li;
            const float* wp = W + (size_t)(k0 + quad * 8) * EMBED + n;
            float bf[8];
            #pragma unroll
            for (int jj = 0; jj < 8; ++jj) bf[jj] = wp[(size_t)jj * EMBED];
            cvt8_hilo(bf, bh[nt], bl[nt]);
        }
        #pragma unroll
        for (int mt = 0; mt < 4; ++mt)
            #pragma unroll
            for (int nt = 0; nt < 2; ++nt) {
                acc[mt][nt] = __builtin_amdgcn_mfma_f32_16x16x32_bf16(ah[mt], bh[nt], acc[mt][nt], 0, 0, 0);
                acc[mt][nt] = __builtin_amdgcn_mfma_f32_16x16x32_bf16(al[mt], bh[nt], acc[mt][nt], 0, 0, 0);
                acc[mt][nt] = __builtin_amdgcn_mfma_f32_16x16x32_bf16(ah[mt], bl[nt], acc[mt][nt], 0, 0, 0);
            }
    }

    const int b = m0 / SEQ;          // 64-row tile never straddles batch (SEQ%64==0)
    const int sbase = m0 - b * SEQ;

    if (z <= 1) {
        ushort_t* __restrict__ dst = z ? ko : qo;
        #pragma unroll
        for (int nt = 0; nt < 2; ++nt) {
            const int gcol = n0 + nt * 16 + li;
            const int h = gcol >> 5, p = gcol & 31;
            const float bb = bias[gcol];
            ushort_t* base = dst + ((size_t)(b * HEADS + h) * SEQ) * PDIM + p;
            #pragma unroll
            for (int mt = 0; mt < 4; ++mt)
                #pragma unroll
                for (int r = 0; r < 4; ++r) {
                    const int s = sbase + mt * 16 + quad * 4 + r;
                    base[(size_t)s * PDIM] = f2bf_rne(acc[mt][nt][r] + bb);
                }
        }
    } else {
        #pragma unroll
        for (int nt = 0; nt < 2; ++nt) {
            const int gcol = n0 + nt * 16 + li;
            const int h = gcol >> 5, p = gcol & 31;
            const float bb = bias[gcol];
            ushort_t* base = vt + ((size_t)(b * HEADS + h) * PDIM + p) * SEQ;
            #pragma unroll
            for (int mt = 0; mt < 4; ++mt) {
                const int s0 = sbase + mt * 16 + quad * 4;
                ushort4 w;
                w.x = f2bf_rne(acc[mt][nt][0] + bb);
                w.y = f2bf_rne(acc[mt][nt][1] + bb);
                w.z = f2bf_rne(acc[mt][nt][2] + bb);
                w.w = f2bf_rne(acc[mt][nt][3] + bb);
                *(ushort4*)&base[s0] = w;
            }
        }
    }
}

// ---------------------------------------------------------------------------
// Kernel 2: flash attention, KV tile = 128 keys (13 iters) + 64-key tail.
// Block = 4 waves x 16 q-rows = 64 rows.  grid 432 x 256.
// Barriers per block: 14 (was 27).  o-rescale per 128 keys (was per 64).
// XCD-aware decode: xcd bid&7 owns heads {2*xcd, 2*xcd+1} -> K/V L2-resident.
// Output bf16 [b][s][h][p].
// ---------------------------------------------------------------------------
__global__ __launch_bounds__(256) void attn_kernel(
    const ushort_t* __restrict__ q, const ushort_t* __restrict__ k,
    const ushort_t* __restrict__ vt, ushort_t* __restrict__ aob)
{
    const int t    = threadIdx.x;
    const int lane = t & 63;
    const int w    = t >> 6;
    const int li   = lane & 15;
    const int quad = lane >> 4;
    // XCD-aware block decode (bid%8 = XCD round-robin heuristic; perf only)
    const int bid = blockIdx.x;
    const int g = bid & 7, j = bid >> 3;           // g: XCD, j: 0..53
    const int bh = g * 2 + (j >= 27 ? 1 : 0);      // 2 heads per XCD
    const int qt = (j >= 27) ? (j - 27) : j;       // q-tile 0..26
    const int b  = bh >> 3, h = bh & 7;
    const int q0 = qt * 64 + w * 16;

    const ushort_t* __restrict__ qb = q  + (size_t)bh * SEQ * PDIM;
    const ushort_t* __restrict__ kb = k  + (size_t)bh * SEQ * PDIM;
    const ushort_t* __restrict__ vb = vt + (size_t)bh * PDIM * SEQ;

    // rows: Ks 40 ushorts (80 B), Vs/Ps 136 ushorts (272 B) -> 16B-aligned
    __shared__ ushort_t Ks[2][128][40];   // 20480 B
    __shared__ ushort_t Vs[2][32][136];   // 17408 B
    __shared__ ushort_t Ps[4][16][136];   // 17408 B  -> 55296 B total

    const bf16x8 qfrag = *(const bf16x8*)(qb + (size_t)(q0 + li) * PDIM + quad * 8);

    // staging (256 threads, 2 x uint4 each for K and V):
    // K: thread t -> key-row t>>1, col half (t&1)*16  (chunks +0, +8)
    // V: thread t -> p-row t>>3, key chunk (t&7)*16   (chunks +0, +8)
    const int krow = t >> 1, kcol = (t & 1) * 16;
    const int vrow = t >> 3, vkey = (t & 7) * 16;
    const ushort_t* kgp = kb + (size_t)krow * PDIM + kcol;
    const ushort_t* vgp = vb + (size_t)vrow * SEQ + vkey;

    f32x4 o0 = {0.f, 0.f, 0.f, 0.f};
    f32x4 o1 = {0.f, 0.f, 0.f, 0.f};
    float m_run = -__builtin_inff(), l_run = 0.f;

    uint4 ka  = *(const uint4*)(kgp);
    uint4 kc  = *(const uint4*)(kgp + 8);
    uint4 va  = *(const uint4*)(vgp);
    uint4 vc  = *(const uint4*)(vgp + 8);

    for (int it = 0; it < NMAIN; ++it) {
        const int p = it & 1;
        *(uint4*)&Ks[p][krow][kcol]     = ka;
        *(uint4*)&Ks[p][krow][kcol + 8] = kc;
        *(uint4*)&Vs[p][vrow][vkey]     = va;
        *(uint4*)&Vs[p][vrow][vkey + 8] = vc;
        __syncthreads();
        if (it + 1 < NMAIN) {
            const size_t ko = (size_t)(it + 1) * KVB * PDIM;
            ka = *(const uint4*)(kgp + ko);
            kc = *(const uint4*)(kgp + ko + 8);
            va = *(const uint4*)(vgp + (it + 1) * KVB);
            vc = *(const uint4*)(vgp + (it + 1) * KVB + 8);
        } else {
            // tail prefetch (64 keys); clamp indices into valid range,
            // duplicated data lands in LDS positions the tail never reads.
            const ushort_t* kt_ = kb + (size_t)(TAIL0 + (krow & 63)) * PDIM + kcol;
            ka = *(const uint4*)(kt_);
            kc = *(const uint4*)(kt_ + 8);
            const ushort_t* vt_ = vb + (size_t)vrow * SEQ + TAIL0 + (vkey & 63);
            va = *(const uint4*)(vt_);
            vc = *(const uint4*)(vt_ + 8);
        }

        // ---- S^T = K * Q^T  (8 sub-tiles of 16 keys) ----
        const f32x4 zero = {0.f, 0.f, 0.f, 0.f};
        f32x4 st[8];
        #pragma unroll
        for (int jt = 0; jt < 8; ++jt) {
            const bf16x8 kf = *(const bf16x8*)&Ks[p][jt * 16 + li][quad * 8];
            st[jt] = __builtin_amdgcn_mfma_f32_16x16x32_bf16(kf, qfrag, zero, 0, 0, 0);
        }

        // ---- online softmax (per-lane stats for query col i=li) ----
        float tm = st[0][0];
        #pragma unroll
        for (int jt = 0; jt < 8; ++jt)
            #pragma unroll
            for (int r = 0; r < 4; ++r) tm = fmaxf(tm, st[jt][r]);
        tm = fmaxf(tm, __shfl_xor(tm, 16));
        tm = fmaxf(tm, __shfl_xor(tm, 32));
        const float mnew  = fmaxf(m_run, tm);
        const float negml = -(mnew * LOG2E);

        float ps = 0.f;
        #pragma unroll
        for (int jt = 0; jt < 8; ++jt) {
            const float p0 = __builtin_amdgcn_exp2f(fmaf(st[jt][0], LOG2E, negml));
            const float p1 = __builtin_amdgcn_exp2f(fmaf(st[jt][1], LOG2E, negml));
            const float p2 = __builtin_amdgcn_exp2f(fmaf(st[jt][2], LOG2E, negml));
            const float p3 = __builtin_amdgcn_exp2f(fmaf(st[jt][3], LOG2E, negml));
            ps += (p0 + p1) + (p2 + p3);
            uint2 pw;
            pw.x = __builtin_amdgcn_perm(__float_as_uint(p1) + 0x8000u,
                                         __float_as_uint(p0) + 0x8000u, 0x07060302u);
            pw.y = __builtin_amdgcn_perm(__float_as_uint(p3) + 0x8000u,
                                         __float_as_uint(p2) + 0x8000u, 0x07060302u);
            *(uint2*)&Ps[w][li][16 * jt + 4 * quad] = pw;
        }
        ps += __shfl_xor(ps, 16);
        ps += __shfl_xor(ps, 32);

        const float alpha = __builtin_amdgcn_exp2f(fmaf(m_run, LOG2E, negml));
        l_run = fmaf(l_run, alpha, ps);
        m_run = mnew;

        float af[4];
        #pragma unroll
        for (int r = 0; r < 4; ++r) af[r] = __shfl(alpha, 4 * quad + r);
        #pragma unroll
        for (int r = 0; r < 4; ++r) { o0[r] *= af[r]; o1[r] *= af[r]; }

        // ---- O += P * V  (4 key-chunks of 32) ----
        #pragma unroll
        for (int c = 0; c < 4; ++c) {
            const bf16x8 pa  = *(const bf16x8*)&Ps[w][li][32 * c + 8 * quad];
            const bf16x8 vf0 = *(const bf16x8*)&Vs[p][li][32 * c + quad * 8];
            const bf16x8 vf1 = *(const bf16x8*)&Vs[p][16 + li][32 * c + quad * 8];
            o0 = __builtin_amdgcn_mfma_f32_16x16x32_bf16(pa, vf0, o0, 0, 0, 0);
            o1 = __builtin_amdgcn_mfma_f32_16x16x32_bf16(pa, vf1, o1, 0, 0, 0);
        }
    }

    // ---- tail: 64 keys at TAIL0, buffer p = NMAIN&1 = 1 ----
    {
        const int p = NMAIN & 1;
        *(uint4*)&Ks[p][krow][kcol]     = ka;
        *(uint4*)&Ks[p][krow][kcol + 8] = kc;
        *(uint4*)&Vs[p][vrow][vkey]     = va;
        *(uint4*)&Vs[p][vrow][vkey + 8] = vc;
        __syncthreads();

        const f32x4 zero = {0.f, 0.f, 0.f, 0.f};
        f32x4 st[4];
        #pragma unroll
        for (int jt = 0; jt < 4; ++jt) {
            const bf16x8 kf = *(const bf16x8*)&Ks[p][jt * 16 + li][quad * 8];
            st[jt] = __builtin_amdgcn_mfma_f32_16x16x32_bf16(kf, qfrag, zero, 0, 0, 0);
        }

        float tm = st[0][0];
        #pragma unroll
        for (int jt = 0; jt < 4; ++jt)
            #pragma unroll
            for (int r = 0; r < 4; ++r) tm = fmaxf(tm, st[jt][r]);
        tm = fmaxf(tm, __shfl_xor(tm, 16));
        tm = fmaxf(tm, __shfl_xor(tm, 32));
        const float mnew  = fmaxf(m_run, tm);
        const float negml = -(mnew * LOG2E);

        float ps = 0.f;
        #pragma unroll
        for (int jt = 0; jt < 4; ++jt) {
            const float p0 = __builtin_amdgcn_exp2f(fmaf(st[jt][0], LOG2E, negml));
            const float p1 = __builtin_amdgcn_exp2f(fmaf(st[jt][1], LOG2E, negml));
            const float p2 = __builtin_amdgcn_exp2f(fmaf(st[jt][2], LOG2E, negml));
            const float p3 = __builtin_amdgcn_exp2f(fmaf(st[jt][3], LOG2E, negml));
            ps += (p0 + p1) + (p2 + p3);
            uint2 pw;
            pw.x = __builtin_amdgcn_perm(__float_as_uint(p1) + 0x8000u,
                                         __float_as_uint(p0) + 0x8000u, 0x07060302u);
            pw.y = __builtin_amdgcn_perm(__float_as_uint(p3) + 0x8000u,
                                         __float_as_uint(p2) + 0x8000u, 0x07060302u);
            *(uint2*)&Ps[w][li][16 * jt + 4 * quad] = pw;
        }
        ps += __shfl_xor(ps, 16);
        ps += __shfl_xor(ps, 32);

        const float alpha = __builtin_amdgcn_exp2f(fmaf(m_run, LOG2E, negml));
        l_run = fmaf(l_run, alpha, ps);
        m_run = mnew;

        float af[4];
        #pragma unroll
        for (int r = 0; r < 4; ++r) af[r] = __shfl(alpha, 4 * quad + r);
        #pragma unroll
        for (int r = 0; r < 4; ++r) { o0[r] *= af[r]; o1[r] *= af[r]; }

        #pragma unroll
        for (int c = 0; c < 2; ++c) {
            const bf16x8 pa  = *(const bf16x8*)&Ps[w][li][32 * c + 8 * quad];
            const bf16x8 vf0 = *(const bf16x8*)&Vs[p][li][32 * c + quad * 8];
            const bf16x8 vf1 = *(const bf16x8*)&Vs[p][16 + li][32 * c + quad * 8];
            o0 = __builtin_amdgcn_mfma_f32_16x16x32_bf16(pa, vf0, o0, 0, 0, 0);
            o1 = __builtin_amdgcn_mfma_f32_16x16x32_bf16(pa, vf1, o1, 0, 0, 0);
        }
    }

    // ---- epilogue: divide by l, write bf16 [b][s][h][p] ----
    float linv[4];
    #pragma unroll
    for (int r = 0; r < 4; ++r) linv[r] = 1.0f / __shfl(l_run, 4 * quad + r);
    #pragma unroll
    for (int r = 0; r < 4; ++r) {
        const int s = q0 + 4 * quad + r;
        ushort_t* row = aob + ((size_t)(b * SEQ + s)) * EMBED + h * PDIM;
        row[li]      = f2bf_rne(o0[r] * linv[r]);
        row[16 + li] = f2bf_rne(o1[r] * linv[r]);
    }
}

// ---------------------------------------------------------------------------
// Kernel 3: output projection, bf16 MFMA, fused Wo fp32->bf16 conversion.
// grid (54, 16) x 64.  Wave tile 64(M) x 16(N), K=256.  out fp32.
// (verbatim from the 119.9 us build)
// ---------------------------------------------------------------------------
__global__ __launch_bounds__(64) void out_gemm_kernel(
    const ushort_t* __restrict__ a, const float* __restrict__ Wo,
    const float* __restrict__ bo, float* __restrict__ out)
{
    const int lane = threadIdx.x, li = lane & 15, quad = lane >> 4;
    const int m0 = blockIdx.x * 64, n0 = blockIdx.y * 16;

    const ushort_t* aph = a + (size_t)(m0 + li) * EMBED + quad * 8;

    f32x4 acc[4];
    #pragma unroll
    for (int mt = 0; mt < 4; ++mt) acc[mt] = (f32x4){0.f, 0.f, 0.f, 0.f};

    #pragma unroll 2
    for (int k0 = 0; k0 < EMBED; k0 += 32) {
        bf16x8 ah[4];
        #pragma unroll
        for (int mt = 0; mt < 4; ++mt)
            ah[mt] = *(const bf16x8*)(aph + (size_t)mt * 16 * EMBED + k0);
        const float* wp = Wo + (size_t)(k0 + quad * 8) * EMBED + n0 + li;
        uint4 pb;
        uint_t* pbv = (uint_t*)&pb;
        #pragma unroll
        for (int j = 0; j < 4; ++j) {
            const uint_t u0 = __float_as_uint(wp[(size_t)(2 * j) * EMBED])     + 0x8000u;
            const uint_t u1 = __float_as_uint(wp[(size_t)(2 * j + 1) * EMBED]) + 0x8000u;
            pbv[j] = __builtin_amdgcn_perm(u1, u0, 0x07060302u);
        }
        v8cast cb; cb.u = pb;
        #pragma unroll
        for (int mt = 0; mt < 4; ++mt)
            acc[mt] = __builtin_amdgcn_mfma_f32_16x16x32_bf16(ah[mt], cb.v, acc[mt], 0, 0, 0);
    }

    const float bb = bo[n0 + li];
    #pragma unroll
    for (int mt = 0; mt < 4; ++mt)
        #pragma unroll
        for (int r = 0; r < 4; ++r) {
            const int row = m0 + mt * 16 + quad * 4 + r;
            out[(size_t)row * EMBED + n0 + li] = acc[mt][r] + bb;
        }
}

// ---------------------------------------------------------------------------
extern "C" void kernel_launch(void* const* d_in, const int* in_sizes, int n_in,
                              void* d_out, int out_size, void* d_ws, size_t ws_size,
                              hipStream_t stream)
{
    const float* x  = (const float*)d_in[0];
    const float* Wq = (const float*)d_in[1];
    const float* bq = (const float*)d_in[2];
    const float* Wk = (const float*)d_in[3];
    const float* bk = (const float*)d_in[4];
    const float* Wv = (const float*)d_in[5];
    const float* bv = (const float*)d_in[6];
    const float* Wo = (const float*)d_in[7];
    const float* bo = (const float*)d_in[8];
    float* out = (float*)d_out;

    ushort_t* ws  = (ushort_t*)d_ws;
    ushort_t* qb  = ws;                      // [b][h][s][p] bf16
    ushort_t* kb  = qb + (size_t)NE;
    ushort_t* vt  = kb + (size_t)NE;         // [b][h][p][s] bf16
    ushort_t* aob = vt + (size_t)NE;         // [b][s][h][p] bf16

    qkv_gemm_kernel<<<dim3(NTOK / 64, 8, 3), 64, 0, stream>>>(
        x, Wq, bq, Wk, bk, Wv, bv, qb, kb, vt);
    attn_kernel<<<dim3(432), 256, 0, stream>>>(qb, kb, vt, aob);
    out_gemm_kernel<<<dim3(NTOK / 64, 16), 64, 0, stream>>>(aob, Wo, bo, out);
}

// Round 4
// 118.093 us; speedup vs baseline: 2.5506x; 1.0122x over previous
//
#include <hip/hip_runtime.h>
#include <math.h>

#define EMBED 256
#define HEADS 8
#define PDIM  32
#define BATCH 2
#define SEQ   1728            // 12*12*12
#define NTOK  (BATCH*SEQ)     // 3456
#define NE    (NTOK*EMBED)    // 884736
#define KVB   128             // keys per attn iteration (main loop)
#define NMAIN 13              // 13*128 = 1664 keys
#define TAIL0 1664            // tail: keys 1664..1727 (64 keys)
#define LOG2E 1.44269504088896f

typedef __attribute__((ext_vector_type(8))) __bf16 bf16x8;
typedef __attribute__((ext_vector_type(4))) float  f32x4;
typedef unsigned short ushort_t;
typedef unsigned int   uint_t;

static __device__ __forceinline__ unsigned short f2bf_rne(float f) {
    union { float f; unsigned u; } x; x.f = f;
    unsigned r = x.u + 0x7fffu + ((x.u >> 16) & 1u);
    return (unsigned short)(r >> 16);
}
union v8cast { uint4 u; bf16x8 v; };

// split 8 floats into bf16 hi (round-half-up) + bf16 lo residual, packed
static __device__ __forceinline__ void cvt8_hilo(const float f[8], bf16x8& hi, bf16x8& lo) {
    uint4 ph, pl;
    uint_t* phv = (uint_t*)&ph; uint_t* plv = (uint_t*)&pl;
    #pragma unroll
    for (int j = 0; j < 4; ++j) {
        const float f0 = f[2 * j], f1 = f[2 * j + 1];
        const uint_t u0 = __float_as_uint(f0) + 0x8000u;
        const uint_t u1 = __float_as_uint(f1) + 0x8000u;
        phv[j] = __builtin_amdgcn_perm(u1, u0, 0x07060302u);
        const float l0 = f0 - __uint_as_float(u0 & 0xFFFF0000u);
        const float l1 = f1 - __uint_as_float(u1 & 0xFFFF0000u);
        plv[j] = __builtin_amdgcn_perm(__float_as_uint(l1) + 0x8000u,
                                       __float_as_uint(l0) + 0x8000u, 0x07060302u);
    }
    v8cast ch; ch.u = ph; hi = ch.v;
    v8cast cl; cl.u = pl; lo = cl.v;
}

// ---------------------------------------------------------------------------
// Kernel 1: QKV projection, fused fp32->bf16 hi/lo conversion + MFMA.
// grid (108, 8, 3) x 64 (1 wave).  Wave tile 32(M) x 32(N), K=256.
// M=32 (was 64): 2592 waves = 2.5/SIMD so cvt-VALU + strided-B-load latency
// overlaps across waves (was 1.27/SIMD, fully exposed).
// Q,K -> [b][h][s][p] bf16;  V -> [b][h][p][s] bf16 (transposed).
// ---------------------------------------------------------------------------
__global__ __launch_bounds__(64) void qkv_gemm_kernel(
    const float* __restrict__ x,
    const float* __restrict__ Wq, const float* __restrict__ bq,
    const float* __restrict__ Wk, const float* __restrict__ bk,
    const float* __restrict__ Wv, const float* __restrict__ bv,
    ushort_t* __restrict__ qo, ushort_t* __restrict__ ko, ushort_t* __restrict__ vt)
{
    const int lane = threadIdx.x, li = lane & 15, quad = lane >> 4;
    const int m0 = blockIdx.x * 32, n0 = blockIdx.y * 32, z = blockIdx.z;
    const float* __restrict__ W    = (z == 0) ? Wq : (z == 1) ? Wk : Wv;
    const float* __restrict__ bias = (z == 0) ? bq : (z == 1) ? bk : bv;

    const float* ap = x + (size_t)(m0 + li) * EMBED + quad * 8;

    f32x4 acc[2][2];
    #pragma unroll
    for (int mt = 0; mt < 2; ++mt)
        #pragma unroll
        for (int nt = 0; nt < 2; ++nt)
            acc[mt][nt] = (f32x4){0.f, 0.f, 0.f, 0.f};

    #pragma unroll 2
    for (int k0 = 0; k0 < EMBED; k0 += 32) {
        bf16x8 ah[2], al[2];
        #pragma unroll
        for (int mt = 0; mt < 2; ++mt) {
            float af[8];
            *(float4*)&af[0] = *(const float4*)(ap + (size_t)mt * 16 * EMBED + k0);
            *(float4*)&af[4] = *(const float4*)(ap + (size_t)mt * 16 * EMBED + k0 + 4);
            cvt8_hilo(af, ah[mt], al[mt]);
        }
        bf16x8 bh[2], bl[2];
        #pragma unroll
        for (int nt = 0; nt < 2; ++nt) {
            const int n = n0 + nt * 16 + li;
            const float* wp = W + (size_t)(k0 + quad * 8) * EMBED + n;
            float bf[8];
            #pragma unroll
            for (int jj = 0; jj < 8; ++jj) bf[jj] = wp[(size_t)jj * EMBED];
            cvt8_hilo(bf, bh[nt], bl[nt]);
        }
        #pragma unroll
        for (int mt = 0; mt < 2; ++mt)
            #pragma unroll
            for (int nt = 0; nt < 2; ++nt) {
                acc[mt][nt] = __builtin_amdgcn_mfma_f32_16x16x32_bf16(ah[mt], bh[nt], acc[mt][nt], 0, 0, 0);
                acc[mt][nt] = __builtin_amdgcn_mfma_f32_16x16x32_bf16(al[mt], bh[nt], acc[mt][nt], 0, 0, 0);
                acc[mt][nt] = __builtin_amdgcn_mfma_f32_16x16x32_bf16(ah[mt], bl[nt], acc[mt][nt], 0, 0, 0);
            }
    }

    const int b = m0 / SEQ;          // 32-row tile never straddles batch (SEQ%32==0)
    const int sbase = m0 - b * SEQ;

    if (z <= 1) {
        ushort_t* __restrict__ dst = z ? ko : qo;
        #pragma unroll
        for (int nt = 0; nt < 2; ++nt) {
            const int gcol = n0 + nt * 16 + li;
            const int h = gcol >> 5, p = gcol & 31;
            const float bb = bias[gcol];
            ushort_t* base = dst + ((size_t)(b * HEADS + h) * SEQ) * PDIM + p;
            #pragma unroll
            for (int mt = 0; mt < 2; ++mt)
                #pragma unroll
                for (int r = 0; r < 4; ++r) {
                    const int s = sbase + mt * 16 + quad * 4 + r;
                    base[(size_t)s * PDIM] = f2bf_rne(acc[mt][nt][r] + bb);
                }
        }
    } else {
        #pragma unroll
        for (int nt = 0; nt < 2; ++nt) {
            const int gcol = n0 + nt * 16 + li;
            const int h = gcol >> 5, p = gcol & 31;
            const float bb = bias[gcol];
            ushort_t* base = vt + ((size_t)(b * HEADS + h) * PDIM + p) * SEQ;
            #pragma unroll
            for (int mt = 0; mt < 2; ++mt) {
                const int s0 = sbase + mt * 16 + quad * 4;
                ushort4 w;
                w.x = f2bf_rne(acc[mt][nt][0] + bb);
                w.y = f2bf_rne(acc[mt][nt][1] + bb);
                w.z = f2bf_rne(acc[mt][nt][2] + bb);
                w.w = f2bf_rne(acc[mt][nt][3] + bb);
                *(ushort4*)&base[s0] = w;
            }
        }
    }
}

// ---------------------------------------------------------------------------
// Kernel 2: flash attention, KV tile = 128 keys (13 iters) + 64-key tail.
// Block = 4 waves x 16 q-rows = 64 rows.  grid 432 x 256.
// (verbatim from the 119.53 us R3 build)
// ---------------------------------------------------------------------------
__global__ __launch_bounds__(256) void attn_kernel(
    const ushort_t* __restrict__ q, const ushort_t* __restrict__ k,
    const ushort_t* __restrict__ vt, ushort_t* __restrict__ aob)
{
    const int t    = threadIdx.x;
    const int lane = t & 63;
    const int w    = t >> 6;
    const int li   = lane & 15;
    const int quad = lane >> 4;
    // XCD-aware block decode (bid%8 = XCD round-robin heuristic; perf only)
    const int bid = blockIdx.x;
    const int g = bid & 7, j = bid >> 3;           // g: XCD, j: 0..53
    const int bh = g * 2 + (j >= 27 ? 1 : 0);      // 2 heads per XCD
    const int qt = (j >= 27) ? (j - 27) : j;       // q-tile 0..26
    const int b  = bh >> 3, h = bh & 7;
    const int q0 = qt * 64 + w * 16;

    const ushort_t* __restrict__ qb = q  + (size_t)bh * SEQ * PDIM;
    const ushort_t* __restrict__ kb = k  + (size_t)bh * SEQ * PDIM;
    const ushort_t* __restrict__ vb = vt + (size_t)bh * PDIM * SEQ;

    // rows: Ks 40 ushorts (80 B), Vs/Ps 136 ushorts (272 B) -> 16B-aligned
    __shared__ ushort_t Ks[2][128][40];   // 20480 B
    __shared__ ushort_t Vs[2][32][136];   // 17408 B
    __shared__ ushort_t Ps[4][16][136];   // 17408 B  -> 55296 B total

    const bf16x8 qfrag = *(const bf16x8*)(qb + (size_t)(q0 + li) * PDIM + quad * 8);

    // staging (256 threads, 2 x uint4 each for K and V)
    const int krow = t >> 1, kcol = (t & 1) * 16;
    const int vrow = t >> 3, vkey = (t & 7) * 16;
    const ushort_t* kgp = kb + (size_t)krow * PDIM + kcol;
    const ushort_t* vgp = vb + (size_t)vrow * SEQ + vkey;

    f32x4 o0 = {0.f, 0.f, 0.f, 0.f};
    f32x4 o1 = {0.f, 0.f, 0.f, 0.f};
    float m_run = -__builtin_inff(), l_run = 0.f;

    uint4 ka  = *(const uint4*)(kgp);
    uint4 kc  = *(const uint4*)(kgp + 8);
    uint4 va  = *(const uint4*)(vgp);
    uint4 vc  = *(const uint4*)(vgp + 8);

    for (int it = 0; it < NMAIN; ++it) {
        const int p = it & 1;
        *(uint4*)&Ks[p][krow][kcol]     = ka;
        *(uint4*)&Ks[p][krow][kcol + 8] = kc;
        *(uint4*)&Vs[p][vrow][vkey]     = va;
        *(uint4*)&Vs[p][vrow][vkey + 8] = vc;
        __syncthreads();
        if (it + 1 < NMAIN) {
            const size_t ko = (size_t)(it + 1) * KVB * PDIM;
            ka = *(const uint4*)(kgp + ko);
            kc = *(const uint4*)(kgp + ko + 8);
            va = *(const uint4*)(vgp + (it + 1) * KVB);
            vc = *(const uint4*)(vgp + (it + 1) * KVB + 8);
        } else {
            // tail prefetch (64 keys); duplicated data never read by tail
            const ushort_t* kt_ = kb + (size_t)(TAIL0 + (krow & 63)) * PDIM + kcol;
            ka = *(const uint4*)(kt_);
            kc = *(const uint4*)(kt_ + 8);
            const ushort_t* vt_ = vb + (size_t)vrow * SEQ + TAIL0 + (vkey & 63);
            va = *(const uint4*)(vt_);
            vc = *(const uint4*)(vt_ + 8);
        }

        // ---- S^T = K * Q^T  (8 sub-tiles of 16 keys) ----
        const f32x4 zero = {0.f, 0.f, 0.f, 0.f};
        f32x4 st[8];
        #pragma unroll
        for (int jt = 0; jt < 8; ++jt) {
            const bf16x8 kf = *(const bf16x8*)&Ks[p][jt * 16 + li][quad * 8];
            st[jt] = __builtin_amdgcn_mfma_f32_16x16x32_bf16(kf, qfrag, zero, 0, 0, 0);
        }

        // ---- online softmax (per-lane stats for query col i=li) ----
        float tm = st[0][0];
        #pragma unroll
        for (int jt = 0; jt < 8; ++jt)
            #pragma unroll
            for (int r = 0; r < 4; ++r) tm = fmaxf(tm, st[jt][r]);
        tm = fmaxf(tm, __shfl_xor(tm, 16));
        tm = fmaxf(tm, __shfl_xor(tm, 32));
        const float mnew  = fmaxf(m_run, tm);
        const float negml = -(mnew * LOG2E);

        float ps = 0.f;
        #pragma unroll
        for (int jt = 0; jt < 8; ++jt) {
            const float p0 = __builtin_amdgcn_exp2f(fmaf(st[jt][0], LOG2E, negml));
            const float p1 = __builtin_amdgcn_exp2f(fmaf(st[jt][1], LOG2E, negml));
            const float p2 = __builtin_amdgcn_exp2f(fmaf(st[jt][2], LOG2E, negml));
            const float p3 = __builtin_amdgcn_exp2f(fmaf(st[jt][3], LOG2E, negml));
            ps += (p0 + p1) + (p2 + p3);
            uint2 pw;
            pw.x = __builtin_amdgcn_perm(__float_as_uint(p1) + 0x8000u,
                                         __float_as_uint(p0) + 0x8000u, 0x07060302u);
            pw.y = __builtin_amdgcn_perm(__float_as_uint(p3) + 0x8000u,
                                         __float_as_uint(p2) + 0x8000u, 0x07060302u);
            *(uint2*)&Ps[w][li][16 * jt + 4 * quad] = pw;
        }
        ps += __shfl_xor(ps, 16);
        ps += __shfl_xor(ps, 32);

        const float alpha = __builtin_amdgcn_exp2f(fmaf(m_run, LOG2E, negml));
        l_run = fmaf(l_run, alpha, ps);
        m_run = mnew;

        float af[4];
        #pragma unroll
        for (int r = 0; r < 4; ++r) af[r] = __shfl(alpha, 4 * quad + r);
        #pragma unroll
        for (int r = 0; r < 4; ++r) { o0[r] *= af[r]; o1[r] *= af[r]; }

        // ---- O += P * V  (4 key-chunks of 32) ----
        #pragma unroll
        for (int c = 0; c < 4; ++c) {
            const bf16x8 pa  = *(const bf16x8*)&Ps[w][li][32 * c + 8 * quad];
            const bf16x8 vf0 = *(const bf16x8*)&Vs[p][li][32 * c + quad * 8];
            const bf16x8 vf1 = *(const bf16x8*)&Vs[p][16 + li][32 * c + quad * 8];
            o0 = __builtin_amdgcn_mfma_f32_16x16x32_bf16(pa, vf0, o0, 0, 0, 0);
            o1 = __builtin_amdgcn_mfma_f32_16x16x32_bf16(pa, vf1, o1, 0, 0, 0);
        }
    }

    // ---- tail: 64 keys at TAIL0, buffer p = NMAIN&1 = 1 ----
    {
        const int p = NMAIN & 1;
        *(uint4*)&Ks[p][krow][kcol]     = ka;
        *(uint4*)&Ks[p][krow][kcol + 8] = kc;
        *(uint4*)&Vs[p][vrow][vkey]     = va;
        *(uint4*)&Vs[p][vrow][vkey + 8] = vc;
        __syncthreads();

        const f32x4 zero = {0.f, 0.f, 0.f, 0.f};
        f32x4 st[4];
        #pragma unroll
        for (int jt = 0; jt < 4; ++jt) {
            const bf16x8 kf = *(const bf16x8*)&Ks[p][jt * 16 + li][quad * 8];
            st[jt] = __builtin_amdgcn_mfma_f32_16x16x32_bf16(kf, qfrag, zero, 0, 0, 0);
        }

        float tm = st[0][0];
        #pragma unroll
        for (int jt = 0; jt < 4; ++jt)
            #pragma unroll
            for (int r = 0; r < 4; ++r) tm = fmaxf(tm, st[jt][r]);
        tm = fmaxf(tm, __shfl_xor(tm, 16));
        tm = fmaxf(tm, __shfl_xor(tm, 32));
        const float mnew  = fmaxf(m_run, tm);
        const float negml = -(mnew * LOG2E);

        float ps = 0.f;
        #pragma unroll
        for (int jt = 0; jt < 4; ++jt) {
            const float p0 = __builtin_amdgcn_exp2f(fmaf(st[jt][0], LOG2E, negml));
            const float p1 = __builtin_amdgcn_exp2f(fmaf(st[jt][1], LOG2E, negml));
            const float p2 = __builtin_amdgcn_exp2f(fmaf(st[jt][2], LOG2E, negml));
            const float p3 = __builtin_amdgcn_exp2f(fmaf(st[jt][3], LOG2E, negml));
            ps += (p0 + p1) + (p2 + p3);
            uint2 pw;
            pw.x = __builtin_amdgcn_perm(__float_as_uint(p1) + 0x8000u,
                                         __float_as_uint(p0) + 0x8000u, 0x07060302u);
            pw.y = __builtin_amdgcn_perm(__float_as_uint(p3) + 0x8000u,
                                         __float_as_uint(p2) + 0x8000u, 0x07060302u);
            *(uint2*)&Ps[w][li][16 * jt + 4 * quad] = pw;
        }
        ps += __shfl_xor(ps, 16);
        ps += __shfl_xor(ps, 32);

        const float alpha = __builtin_amdgcn_exp2f(fmaf(m_run, LOG2E, negml));
        l_run = fmaf(l_run, alpha, ps);
        m_run = mnew;

        float af[4];
        #pragma unroll
        for (int r = 0; r < 4; ++r) af[r] = __shfl(alpha, 4 * quad + r);
        #pragma unroll
        for (int r = 0; r < 4; ++r) { o0[r] *= af[r]; o1[r] *= af[r]; }

        #pragma unroll
        for (int c = 0; c < 2; ++c) {
            const bf16x8 pa  = *(const bf16x8*)&Ps[w][li][32 * c + 8 * quad];
            const bf16x8 vf0 = *(const bf16x8*)&Vs[p][li][32 * c + quad * 8];
            const bf16x8 vf1 = *(const bf16x8*)&Vs[p][16 + li][32 * c + quad * 8];
            o0 = __builtin_amdgcn_mfma_f32_16x16x32_bf16(pa, vf0, o0, 0, 0, 0);
            o1 = __builtin_amdgcn_mfma_f32_16x16x32_bf16(pa, vf1, o1, 0, 0, 0);
        }
    }

    // ---- epilogue: divide by l, write bf16 [b][s][h][p] ----
    float linv[4];
    #pragma unroll
    for (int r = 0; r < 4; ++r) linv[r] = 1.0f / __shfl(l_run, 4 * quad + r);
    #pragma unroll
    for (int r = 0; r < 4; ++r) {
        const int s = q0 + 4 * quad + r;
        ushort_t* row = aob + ((size_t)(b * SEQ + s)) * EMBED + h * PDIM;
        row[li]      = f2bf_rne(o0[r] * linv[r]);
        row[16 + li] = f2bf_rne(o1[r] * linv[r]);
    }
}

// ---------------------------------------------------------------------------
// Kernel 3: output projection, bf16 MFMA, fused Wo fp32->bf16 conversion.
// grid (108, 16) x 64.  Wave tile 32(M) x 16(N), K=256.  out fp32.
// M=32 (was 64): 1728 waves = 1.7/SIMD (was 0.84 -- sub-unity occupancy).
// ---------------------------------------------------------------------------
__global__ __launch_bounds__(64) void out_gemm_kernel(
    const ushort_t* __restrict__ a, const float* __restrict__ Wo,
    const float* __restrict__ bo, float* __restrict__ out)
{
    const int lane = threadIdx.x, li = lane & 15, quad = lane >> 4;
    const int m0 = blockIdx.x * 32, n0 = blockIdx.y * 16;

    const ushort_t* aph = a + (size_t)(m0 + li) * EMBED + quad * 8;

    f32x4 acc[2];
    #pragma unroll
    for (int mt = 0; mt < 2; ++mt) acc[mt] = (f32x4){0.f, 0.f, 0.f, 0.f};

    #pragma unroll 2
    for (int k0 = 0; k0 < EMBED; k0 += 32) {
        bf16x8 ah[2];
        #pragma unroll
        for (int mt = 0; mt < 2; ++mt)
            ah[mt] = *(const bf16x8*)(aph + (size_t)mt * 16 * EMBED + k0);
        const float* wp = Wo + (size_t)(k0 + quad * 8) * EMBED + n0 + li;
        uint4 pb;
        uint_t* pbv = (uint_t*)&pb;
        #pragma unroll
        for (int j = 0; j < 4; ++j) {
            const uint_t u0 = __float_as_uint(wp[(size_t)(2 * j) * EMBED])     + 0x8000u;
            const uint_t u1 = __float_as_uint(wp[(size_t)(2 * j + 1) * EMBED]) + 0x8000u;
            pbv[j] = __builtin_amdgcn_perm(u1, u0, 0x07060302u);
        }
        v8cast cb; cb.u = pb;
        #pragma unroll
        for (int mt = 0; mt < 2; ++mt)
            acc[mt] = __builtin_amdgcn_mfma_f32_16x16x32_bf16(ah[mt], cb.v, acc[mt], 0, 0, 0);
    }

    const float bb = bo[n0 + li];
    #pragma unroll
    for (int mt = 0; mt < 2; ++mt)
        #pragma unroll
        for (int r = 0; r < 4; ++r) {
            const int row = m0 + mt * 16 + quad * 4 + r;
            out[(size_t)row * EMBED + n0 + li] = acc[mt][r] + bb;
        }
}

// ---------------------------------------------------------------------------
extern "C" void kernel_launch(void* const* d_in, const int* in_sizes, int n_in,
                              void* d_out, int out_size, void* d_ws, size_t ws_size,
                              hipStream_t stream)
{
    const float* x  = (const float*)d_in[0];
    const float* Wq = (const float*)d_in[1];
    const float* bq = (const float*)d_in[2];
    const float* Wk = (const float*)d_in[3];
    const float* bk = (const float*)d_in[4];
    const float* Wv = (const float*)d_in[5];
    const float* bv = (const float*)d_in[6];
    const float* Wo = (const float*)d_in[7];
    const float* bo = (const float*)d_in[8];
    float* out = (float*)d_out;

    ushort_t* ws  = (ushort_t*)d_ws;
    ushort_t* qb  = ws;                      // [b][h][s][p] bf16
    ushort_t* kb  = qb + (size_t)NE;
    ushort_t* vt  = kb + (size_t)NE;         // [b][h][p][s] bf16
    ushort_t* aob = vt + (size_t)NE;         // [b][s][h][p] bf16

    qkv_gemm_kernel<<<dim3(NTOK / 32, 8, 3), 64, 0, stream>>>(
        x, Wq, bq, Wk, bk, Wv, bv, qb, kb, vt);
    attn_kernel<<<dim3(432), 256, 0, stream>>>(qb, kb, vt, aob);
    out_gemm_kernel<<<dim3(NTOK / 32, 16), 64, 0, stream>>>(aob, Wo, bo, out);
}

// Round 5
// 113.655 us; speedup vs baseline: 2.6501x; 1.0390x over previous
//
#include <hip/hip_runtime.h>
#include <math.h>

#define EMBED 256
#define HEADS 8
#define PDIM  32
#define BATCH 2
#define SEQ   1728            // 12*12*12
#define NTOK  (BATCH*SEQ)     // 3456
#define NE    (NTOK*EMBED)    // 884736
#define KVB   128             // keys per attn iteration (main loop)
#define NMAIN 13              // 13*128 = 1664 keys
#define TAIL0 1664            // tail: keys 1664..1727 (64 keys)
#define LOG2E 1.44269504088896f

typedef __attribute__((ext_vector_type(8))) __bf16 bf16x8;
typedef __attribute__((ext_vector_type(4))) float  f32x4;
typedef unsigned short ushort_t;
typedef unsigned int   uint_t;

static __device__ __forceinline__ unsigned short f2bf_rne(float f) {
    union { float f; unsigned u; } x; x.f = f;
    unsigned r = x.u + 0x7fffu + ((x.u >> 16) & 1u);
    return (unsigned short)(r >> 16);
}
union v8cast { uint4 u; bf16x8 v; };

// split 8 floats into bf16 hi (round-half-up) + bf16 lo residual, packed
static __device__ __forceinline__ void cvt8_hilo(const float f[8], bf16x8& hi, bf16x8& lo) {
    uint4 ph, pl;
    uint_t* phv = (uint_t*)&ph; uint_t* plv = (uint_t*)&pl;
    #pragma unroll
    for (int j = 0; j < 4; ++j) {
        const float f0 = f[2 * j], f1 = f[2 * j + 1];
        const uint_t u0 = __float_as_uint(f0) + 0x8000u;
        const uint_t u1 = __float_as_uint(f1) + 0x8000u;
        phv[j] = __builtin_amdgcn_perm(u1, u0, 0x07060302u);
        const float l0 = f0 - __uint_as_float(u0 & 0xFFFF0000u);
        const float l1 = f1 - __uint_as_float(u1 & 0xFFFF0000u);
        plv[j] = __builtin_amdgcn_perm(__float_as_uint(l1) + 0x8000u,
                                       __float_as_uint(l0) + 0x8000u, 0x07060302u);
    }
    v8cast ch; ch.u = ph; hi = ch.v;
    v8cast cl; cl.u = pl; lo = cl.v;
}

// ---------------------------------------------------------------------------
// Kernel 1: QKV projection.  Block = 256 thr (4 waves), tile 64(M) x 64(N),
// wave (wm,wn) owns a 32x32 quadrant.  Per k-step (BK=32) the block
// cooperatively stages A(64x32) and B(32x64) fp32 -> hi/lo bf16 into
// double-buffered LDS (rows padded to 40 ushorts = 80 B -> 2-way-free banks).
// cvt work/thread halves vs R4; B loads become coalesced 256 B segments.
// grid (54, 4, 3) x 256.  Q,K -> [b][h][s][p];  V -> [b][h][p][s].
// ---------------------------------------------------------------------------
__global__ __launch_bounds__(256) void qkv_gemm_kernel(
    const float* __restrict__ x,
    const float* __restrict__ Wq, const float* __restrict__ bq,
    const float* __restrict__ Wk, const float* __restrict__ bk,
    const float* __restrict__ Wv, const float* __restrict__ bv,
    ushort_t* __restrict__ qo, ushort_t* __restrict__ ko, ushort_t* __restrict__ vt)
{
    const int t = threadIdx.x;
    const int lane = t & 63, li = lane & 15, quad = lane >> 4;
    const int w = t >> 6, wm = w >> 1, wn = w & 1;
    const int m0 = blockIdx.x * 64, n0 = blockIdx.y * 64, z = blockIdx.z;
    const float* __restrict__ W    = (z == 0) ? Wq : (z == 1) ? Wk : Wv;
    const float* __restrict__ bias = (z == 0) ? bq : (z == 1) ? bk : bv;

    __shared__ ushort_t Ah[2][64][40];   // [buf][m][k]  10240 B
    __shared__ ushort_t Al[2][64][40];
    __shared__ ushort_t Bh[2][64][40];   // [buf][n][k]
    __shared__ ushort_t Bl[2][64][40];   // total 40960 B

    // staging assignment: A row ar / k-chunk ac; B col bn / k-chunk bk8
    const int ar = t >> 2, ac = (t & 3) * 8;
    const int bn = t & 63, bk8 = (t >> 6) * 8;

    const float* agp = x + (size_t)(m0 + ar) * EMBED + ac;
    const float* bgp = W + (size_t)bk8 * EMBED + n0 + bn;

    float areg[8], breg[8];
    *(float4*)&areg[0] = *(const float4*)(agp);
    *(float4*)&areg[4] = *(const float4*)(agp + 4);
    #pragma unroll
    for (int j = 0; j < 8; ++j) breg[j] = bgp[(size_t)j * EMBED];

    f32x4 acc[2][2];
    #pragma unroll
    for (int mt = 0; mt < 2; ++mt)
        #pragma unroll
        for (int nt = 0; nt < 2; ++nt)
            acc[mt][nt] = (f32x4){0.f, 0.f, 0.f, 0.f};

    for (int ks = 0; ks < 8; ++ks) {
        const int p = ks & 1;
        {
            bf16x8 h, l;
            cvt8_hilo(areg, h, l);
            v8cast ch; ch.v = h; *(uint4*)&Ah[p][ar][ac] = ch.u;
            v8cast cl; cl.v = l; *(uint4*)&Al[p][ar][ac] = cl.u;
        }
        {
            bf16x8 h, l;
            cvt8_hilo(breg, h, l);
            v8cast ch; ch.v = h; *(uint4*)&Bh[p][bn][bk8] = ch.u;
            v8cast cl; cl.v = l; *(uint4*)&Bl[p][bn][bk8] = cl.u;
        }
        __syncthreads();
        if (ks < 7) {
            const int k1 = (ks + 1) * 32;
            *(float4*)&areg[0] = *(const float4*)(agp + k1);
            *(float4*)&areg[4] = *(const float4*)(agp + k1 + 4);
            const float* bg = bgp + (size_t)k1 * EMBED;
            #pragma unroll
            for (int j = 0; j < 8; ++j) breg[j] = bg[(size_t)j * EMBED];
        }
        bf16x8 ah[2], al_[2], bh[2], bl_[2];
        #pragma unroll
        for (int mt = 0; mt < 2; ++mt) {
            ah[mt]  = *(const bf16x8*)&Ah[p][wm * 32 + mt * 16 + li][quad * 8];
            al_[mt] = *(const bf16x8*)&Al[p][wm * 32 + mt * 16 + li][quad * 8];
        }
        #pragma unroll
        for (int nt = 0; nt < 2; ++nt) {
            bh[nt]  = *(const bf16x8*)&Bh[p][wn * 32 + nt * 16 + li][quad * 8];
            bl_[nt] = *(const bf16x8*)&Bl[p][wn * 32 + nt * 16 + li][quad * 8];
        }
        #pragma unroll
        for (int mt = 0; mt < 2; ++mt)
            #pragma unroll
            for (int nt = 0; nt < 2; ++nt) {
                acc[mt][nt] = __builtin_amdgcn_mfma_f32_16x16x32_bf16(ah[mt],  bh[nt],  acc[mt][nt], 0, 0, 0);
                acc[mt][nt] = __builtin_amdgcn_mfma_f32_16x16x32_bf16(al_[mt], bh[nt],  acc[mt][nt], 0, 0, 0);
                acc[mt][nt] = __builtin_amdgcn_mfma_f32_16x16x32_bf16(ah[mt],  bl_[nt], acc[mt][nt], 0, 0, 0);
            }
    }

    const int b = m0 / SEQ;          // 64-row tile never straddles batch (SEQ%64==0)
    const int sbase = m0 - b * SEQ + wm * 32;

    if (z <= 1) {
        ushort_t* __restrict__ dst = z ? ko : qo;
        #pragma unroll
        for (int nt = 0; nt < 2; ++nt) {
            const int gcol = n0 + wn * 32 + nt * 16 + li;
            const int h = gcol >> 5, p = gcol & 31;
            const float bb = bias[gcol];
            ushort_t* base = dst + ((size_t)(b * HEADS + h) * SEQ) * PDIM + p;
            #pragma unroll
            for (int mt = 0; mt < 2; ++mt)
                #pragma unroll
                for (int r = 0; r < 4; ++r) {
                    const int s = sbase + mt * 16 + quad * 4 + r;
                    base[(size_t)s * PDIM] = f2bf_rne(acc[mt][nt][r] + bb);
                }
        }
    } else {
        #pragma unroll
        for (int nt = 0; nt < 2; ++nt) {
            const int gcol = n0 + wn * 32 + nt * 16 + li;
            const int h = gcol >> 5, p = gcol & 31;
            const float bb = bias[gcol];
            ushort_t* base = vt + ((size_t)(b * HEADS + h) * PDIM + p) * SEQ;
            #pragma unroll
            for (int mt = 0; mt < 2; ++mt) {
                const int s0 = sbase + mt * 16 + quad * 4;
                ushort4 wv4;
                wv4.x = f2bf_rne(acc[mt][nt][0] + bb);
                wv4.y = f2bf_rne(acc[mt][nt][1] + bb);
                wv4.z = f2bf_rne(acc[mt][nt][2] + bb);
                wv4.w = f2bf_rne(acc[mt][nt][3] + bb);
                *(ushort4*)&base[s0] = wv4;
            }
        }
    }
}

// ---------------------------------------------------------------------------
// Kernel 2: flash attention, KV tile = 128 keys (13 iters) + 64-key tail.
// Block = 4 waves x 16 q-rows = 64 rows.  grid 432 x 256.
// (verbatim from the 118.09 us R4 build)
// ---------------------------------------------------------------------------
__global__ __launch_bounds__(256) void attn_kernel(
    const ushort_t* __restrict__ q, const ushort_t* __restrict__ k,
    const ushort_t* __restrict__ vt, ushort_t* __restrict__ aob)
{
    const int t    = threadIdx.x;
    const int lane = t & 63;
    const int w    = t >> 6;
    const int li   = lane & 15;
    const int quad = lane >> 4;
    // XCD-aware block decode (bid%8 = XCD round-robin heuristic; perf only)
    const int bid = blockIdx.x;
    const int g = bid & 7, j = bid >> 3;           // g: XCD, j: 0..53
    const int bh = g * 2 + (j >= 27 ? 1 : 0);      // 2 heads per XCD
    const int qt = (j >= 27) ? (j - 27) : j;       // q-tile 0..26
    const int b  = bh >> 3, h = bh & 7;
    const int q0 = qt * 64 + w * 16;

    const ushort_t* __restrict__ qb = q  + (size_t)bh * SEQ * PDIM;
    const ushort_t* __restrict__ kb = k  + (size_t)bh * SEQ * PDIM;
    const ushort_t* __restrict__ vb = vt + (size_t)bh * PDIM * SEQ;

    // rows: Ks 40 ushorts (80 B), Vs/Ps 136 ushorts (272 B) -> 16B-aligned
    __shared__ ushort_t Ks[2][128][40];   // 20480 B
    __shared__ ushort_t Vs[2][32][136];   // 17408 B
    __shared__ ushort_t Ps[4][16][136];   // 17408 B  -> 55296 B total

    const bf16x8 qfrag = *(const bf16x8*)(qb + (size_t)(q0 + li) * PDIM + quad * 8);

    // staging (256 threads, 2 x uint4 each for K and V)
    const int krow = t >> 1, kcol = (t & 1) * 16;
    const int vrow = t >> 3, vkey = (t & 7) * 16;
    const ushort_t* kgp = kb + (size_t)krow * PDIM + kcol;
    const ushort_t* vgp = vb + (size_t)vrow * SEQ + vkey;

    f32x4 o0 = {0.f, 0.f, 0.f, 0.f};
    f32x4 o1 = {0.f, 0.f, 0.f, 0.f};
    float m_run = -__builtin_inff(), l_run = 0.f;

    uint4 ka  = *(const uint4*)(kgp);
    uint4 kc  = *(const uint4*)(kgp + 8);
    uint4 va  = *(const uint4*)(vgp);
    uint4 vc  = *(const uint4*)(vgp + 8);

    for (int it = 0; it < NMAIN; ++it) {
        const int p = it & 1;
        *(uint4*)&Ks[p][krow][kcol]     = ka;
        *(uint4*)&Ks[p][krow][kcol + 8] = kc;
        *(uint4*)&Vs[p][vrow][vkey]     = va;
        *(uint4*)&Vs[p][vrow][vkey + 8] = vc;
        __syncthreads();
        if (it + 1 < NMAIN) {
            const size_t ko = (size_t)(it + 1) * KVB * PDIM;
            ka = *(const uint4*)(kgp + ko);
            kc = *(const uint4*)(kgp + ko + 8);
            va = *(const uint4*)(vgp + (it + 1) * KVB);
            vc = *(const uint4*)(vgp + (it + 1) * KVB + 8);
        } else {
            // tail prefetch (64 keys); duplicated data never read by tail
            const ushort_t* kt_ = kb + (size_t)(TAIL0 + (krow & 63)) * PDIM + kcol;
            ka = *(const uint4*)(kt_);
            kc = *(const uint4*)(kt_ + 8);
            const ushort_t* vt_ = vb + (size_t)vrow * SEQ + TAIL0 + (vkey & 63);
            va = *(const uint4*)(vt_);
            vc = *(const uint4*)(vt_ + 8);
        }

        // ---- S^T = K * Q^T  (8 sub-tiles of 16 keys) ----
        const f32x4 zero = {0.f, 0.f, 0.f, 0.f};
        f32x4 st[8];
        #pragma unroll
        for (int jt = 0; jt < 8; ++jt) {
            const bf16x8 kf = *(const bf16x8*)&Ks[p][jt * 16 + li][quad * 8];
            st[jt] = __builtin_amdgcn_mfma_f32_16x16x32_bf16(kf, qfrag, zero, 0, 0, 0);
        }

        // ---- online softmax (per-lane stats for query col i=li) ----
        float tm = st[0][0];
        #pragma unroll
        for (int jt = 0; jt < 8; ++jt)
            #pragma unroll
            for (int r = 0; r < 4; ++r) tm = fmaxf(tm, st[jt][r]);
        tm = fmaxf(tm, __shfl_xor(tm, 16));
        tm = fmaxf(tm, __shfl_xor(tm, 32));
        const float mnew  = fmaxf(m_run, tm);
        const float negml = -(mnew * LOG2E);

        float ps = 0.f;
        #pragma unroll
        for (int jt = 0; jt < 8; ++jt) {
            const float p0 = __builtin_amdgcn_exp2f(fmaf(st[jt][0], LOG2E, negml));
            const float p1 = __builtin_amdgcn_exp2f(fmaf(st[jt][1], LOG2E, negml));
            const float p2 = __builtin_amdgcn_exp2f(fmaf(st[jt][2], LOG2E, negml));
            const float p3 = __builtin_amdgcn_exp2f(fmaf(st[jt][3], LOG2E, negml));
            ps += (p0 + p1) + (p2 + p3);
            uint2 pw;
            pw.x = __builtin_amdgcn_perm(__float_as_uint(p1) + 0x8000u,
                                         __float_as_uint(p0) + 0x8000u, 0x07060302u);
            pw.y = __builtin_amdgcn_perm(__float_as_uint(p3) + 0x8000u,
                                         __float_as_uint(p2) + 0x8000u, 0x07060302u);
            *(uint2*)&Ps[w][li][16 * jt + 4 * quad] = pw;
        }
        ps += __shfl_xor(ps, 16);
        ps += __shfl_xor(ps, 32);

        const float alpha = __builtin_amdgcn_exp2f(fmaf(m_run, LOG2E, negml));
        l_run = fmaf(l_run, alpha, ps);
        m_run = mnew;

        float af[4];
        #pragma unroll
        for (int r = 0; r < 4; ++r) af[r] = __shfl(alpha, 4 * quad + r);
        #pragma unroll
        for (int r = 0; r < 4; ++r) { o0[r] *= af[r]; o1[r] *= af[r]; }

        // ---- O += P * V  (4 key-chunks of 32) ----
        #pragma unroll
        for (int c = 0; c < 4; ++c) {
            const bf16x8 pa  = *(const bf16x8*)&Ps[w][li][32 * c + 8 * quad];
            const bf16x8 vf0 = *(const bf16x8*)&Vs[p][li][32 * c + quad * 8];
            const bf16x8 vf1 = *(const bf16x8*)&Vs[p][16 + li][32 * c + quad * 8];
            o0 = __builtin_amdgcn_mfma_f32_16x16x32_bf16(pa, vf0, o0, 0, 0, 0);
            o1 = __builtin_amdgcn_mfma_f32_16x16x32_bf16(pa, vf1, o1, 0, 0, 0);
        }
    }

    // ---- tail: 64 keys at TAIL0, buffer p = NMAIN&1 = 1 ----
    {
        const int p = NMAIN & 1;
        *(uint4*)&Ks[p][krow][kcol]     = ka;
        *(uint4*)&Ks[p][krow][kcol + 8] = kc;
        *(uint4*)&Vs[p][vrow][vkey]     = va;
        *(uint4*)&Vs[p][vrow][vkey + 8] = vc;
        __syncthreads();

        const f32x4 zero = {0.f, 0.f, 0.f, 0.f};
        f32x4 st[4];
        #pragma unroll
        for (int jt = 0; jt < 4; ++jt) {
            const bf16x8 kf = *(const bf16x8*)&Ks[p][jt * 16 + li][quad * 8];
            st[jt] = __builtin_amdgcn_mfma_f32_16x16x32_bf16(kf, qfrag, zero, 0, 0, 0);
        }

        float tm = st[0][0];
        #pragma unroll
        for (int jt = 0; jt < 4; ++jt)
            #pragma unroll
            for (int r = 0; r < 4; ++r) tm = fmaxf(tm, st[jt][r]);
        tm = fmaxf(tm, __shfl_xor(tm, 16));
        tm = fmaxf(tm, __shfl_xor(tm, 32));
        const float mnew  = fmaxf(m_run, tm);
        const float negml = -(mnew * LOG2E);

        float ps = 0.f;
        #pragma unroll
        for (int jt = 0; jt < 4; ++jt) {
            const float p0 = __builtin_amdgcn_exp2f(fmaf(st[jt][0], LOG2E, negml));
            const float p1 = __builtin_amdgcn_exp2f(fmaf(st[jt][1], LOG2E, negml));
            const float p2 = __builtin_amdgcn_exp2f(fmaf(st[jt][2], LOG2E, negml));
            const float p3 = __builtin_amdgcn_exp2f(fmaf(st[jt][3], LOG2E, negml));
            ps += (p0 + p1) + (p2 + p3);
            uint2 pw;
            pw.x = __builtin_amdgcn_perm(__float_as_uint(p1) + 0x8000u,
                                         __float_as_uint(p0) + 0x8000u, 0x07060302u);
            pw.y = __builtin_amdgcn_perm(__float_as_uint(p3) + 0x8000u,
                                         __float_as_uint(p2) + 0x8000u, 0x07060302u);
            *(uint2*)&Ps[w][li][16 * jt + 4 * quad] = pw;
        }
        ps += __shfl_xor(ps, 16);
        ps += __shfl_xor(ps, 32);

        const float alpha = __builtin_amdgcn_exp2f(fmaf(m_run, LOG2E, negml));
        l_run = fmaf(l_run, alpha, ps);
        m_run = mnew;

        float af[4];
        #pragma unroll
        for (int r = 0; r < 4; ++r) af[r] = __shfl(alpha, 4 * quad + r);
        #pragma unroll
        for (int r = 0; r < 4; ++r) { o0[r] *= af[r]; o1[r] *= af[r]; }

        #pragma unroll
        for (int c = 0; c < 2; ++c) {
            const bf16x8 pa  = *(const bf16x8*)&Ps[w][li][32 * c + 8 * quad];
            const bf16x8 vf0 = *(const bf16x8*)&Vs[p][li][32 * c + quad * 8];
            const bf16x8 vf1 = *(const bf16x8*)&Vs[p][16 + li][32 * c + quad * 8];
            o0 = __builtin_amdgcn_mfma_f32_16x16x32_bf16(pa, vf0, o0, 0, 0, 0);
            o1 = __builtin_amdgcn_mfma_f32_16x16x32_bf16(pa, vf1, o1, 0, 0, 0);
        }
    }

    // ---- epilogue: divide by l, write bf16 [b][s][h][p] ----
    float linv[4];
    #pragma unroll
    for (int r = 0; r < 4; ++r) linv[r] = 1.0f / __shfl(l_run, 4 * quad + r);
    #pragma unroll
    for (int r = 0; r < 4; ++r) {
        const int s = q0 + 4 * quad + r;
        ushort_t* row = aob + ((size_t)(b * SEQ + s)) * EMBED + h * PDIM;
        row[li]      = f2bf_rne(o0[r] * linv[r]);
        row[16 + li] = f2bf_rne(o1[r] * linv[r]);
    }
}

// ---------------------------------------------------------------------------
// Kernel 3: output projection, bf16 MFMA, fused Wo fp32->bf16 conversion.
// grid (108, 16) x 64.  Wave tile 32(M) x 16(N), K=256.  out fp32.
// (verbatim from the 118.09 us R4 build)
// ---------------------------------------------------------------------------
__global__ __launch_bounds__(64) void out_gemm_kernel(
    const ushort_t* __restrict__ a, const float* __restrict__ Wo,
    const float* __restrict__ bo, float* __restrict__ out)
{
    const int lane = threadIdx.x, li = lane & 15, quad = lane >> 4;
    const int m0 = blockIdx.x * 32, n0 = blockIdx.y * 16;

    const ushort_t* aph = a + (size_t)(m0 + li) * EMBED + quad * 8;

    f32x4 acc[2];
    #pragma unroll
    for (int mt = 0; mt < 2; ++mt) acc[mt] = (f32x4){0.f, 0.f, 0.f, 0.f};

    #pragma unroll 2
    for (int k0 = 0; k0 < EMBED; k0 += 32) {
        bf16x8 ah[2];
        #pragma unroll
        for (int mt = 0; mt < 2; ++mt)
            ah[mt] = *(const bf16x8*)(aph + (size_t)mt * 16 * EMBED + k0);
        const float* wp = Wo + (size_t)(k0 + quad * 8) * EMBED + n0 + li;
        uint4 pb;
        uint_t* pbv = (uint_t*)&pb;
        #pragma unroll
        for (int j = 0; j < 4; ++j) {
            const uint_t u0 = __float_as_uint(wp[(size_t)(2 * j) * EMBED])     + 0x8000u;
            const uint_t u1 = __float_as_uint(wp[(size_t)(2 * j + 1) * EMBED]) + 0x8000u;
            pbv[j] = __builtin_amdgcn_perm(u1, u0, 0x07060302u);
        }
        v8cast cb; cb.u = pb;
        #pragma unroll
        for (int mt = 0; mt < 2; ++mt)
            acc[mt] = __builtin_amdgcn_mfma_f32_16x16x32_bf16(ah[mt], cb.v, acc[mt], 0, 0, 0);
    }

    const float bb = bo[n0 + li];
    #pragma unroll
    for (int mt = 0; mt < 2; ++mt)
        #pragma unroll
        for (int r = 0; r < 4; ++r) {
            const int row = m0 + mt * 16 + quad * 4 + r;
            out[(size_t)row * EMBED + n0 + li] = acc[mt][r] + bb;
        }
}

// ---------------------------------------------------------------------------
extern "C" void kernel_launch(void* const* d_in, const int* in_sizes, int n_in,
                              void* d_out, int out_size, void* d_ws, size_t ws_size,
                              hipStream_t stream)
{
    const float* x  = (const float*)d_in[0];
    const float* Wq = (const float*)d_in[1];
    const float* bq = (const float*)d_in[2];
    const float* Wk = (const float*)d_in[3];
    const float* bk = (const float*)d_in[4];
    const float* Wv = (const float*)d_in[5];
    const float* bv = (const float*)d_in[6];
    const float* Wo = (const float*)d_in[7];
    const float* bo = (const float*)d_in[8];
    float* out = (float*)d_out;

    ushort_t* ws  = (ushort_t*)d_ws;
    ushort_t* qb  = ws;                      // [b][h][s][p] bf16
    ushort_t* kb  = qb + (size_t)NE;
    ushort_t* vt  = kb + (size_t)NE;         // [b][h][p][s] bf16
    ushort_t* aob = vt + (size_t)NE;         // [b][s][h][p] bf16

    qkv_gemm_kernel<<<dim3(NTOK / 64, EMBED / 64, 3), 256, 0, stream>>>(
        x, Wq, bq, Wk, bk, Wv, bv, qb, kb, vt);
    attn_kernel<<<dim3(432), 256, 0, stream>>>(qb, kb, vt, aob);
    out_gemm_kernel<<<dim3(NTOK / 32, 16), 64, 0, stream>>>(aob, Wo, bo, out);
}

// Round 6
// 113.609 us; speedup vs baseline: 2.6512x; 1.0004x over previous
//
#include <hip/hip_runtime.h>
#include <math.h>

#define EMBED 256
#define HEADS 8
#define PDIM  32
#define BATCH 2
#define SEQ   1728            // 12*12*12
#define NTOK  (BATCH*SEQ)     // 3456
#define NE    (NTOK*EMBED)    // 884736
#define LOG2E 1.44269504088896f

typedef __attribute__((ext_vector_type(8))) __bf16 bf16x8;
typedef __attribute__((ext_vector_type(4))) float  f32x4;
typedef unsigned short ushort_t;
typedef unsigned int   uint_t;

static __device__ __forceinline__ unsigned short f2bf_rne(float f) {
    union { float f; unsigned u; } x; x.f = f;
    unsigned r = x.u + 0x7fffu + ((x.u >> 16) & 1u);
    return (unsigned short)(r >> 16);
}
union v8cast { uint4 u; bf16x8 v; };

// split 8 floats into bf16 hi (round-half-up) + bf16 lo residual, packed
static __device__ __forceinline__ void cvt8_hilo(const float f[8], bf16x8& hi, bf16x8& lo) {
    uint4 ph, pl;
    uint_t* phv = (uint_t*)&ph; uint_t* plv = (uint_t*)&pl;
    #pragma unroll
    for (int j = 0; j < 4; ++j) {
        const float f0 = f[2 * j], f1 = f[2 * j + 1];
        const uint_t u0 = __float_as_uint(f0) + 0x8000u;
        const uint_t u1 = __float_as_uint(f1) + 0x8000u;
        phv[j] = __builtin_amdgcn_perm(u1, u0, 0x07060302u);
        const float l0 = f0 - __uint_as_float(u0 & 0xFFFF0000u);
        const float l1 = f1 - __uint_as_float(u1 & 0xFFFF0000u);
        plv[j] = __builtin_amdgcn_perm(__float_as_uint(l1) + 0x8000u,
                                       __float_as_uint(l0) + 0x8000u, 0x07060302u);
    }
    v8cast ch; ch.u = ph; hi = ch.v;
    v8cast cl; cl.u = pl; lo = cl.v;
}

// ---------------------------------------------------------------------------
// Kernel 1: QKV projection (verbatim R5 113.7us build).  Block = 256 thr
// (4 waves), tile 64Mx64N, cooperative LDS-staged hi/lo conversion, dbuf.
// grid (54, 4, 3) x 256.  Q,K -> [b][h][s][p];  V -> [b][h][p][s].
// ---------------------------------------------------------------------------
__global__ __launch_bounds__(256) void qkv_gemm_kernel(
    const float* __restrict__ x,
    const float* __restrict__ Wq, const float* __restrict__ bq,
    const float* __restrict__ Wk, const float* __restrict__ bk,
    const float* __restrict__ Wv, const float* __restrict__ bv,
    ushort_t* __restrict__ qo, ushort_t* __restrict__ ko, ushort_t* __restrict__ vt)
{
    const int t = threadIdx.x;
    const int lane = t & 63, li = lane & 15, quad = lane >> 4;
    const int w = t >> 6, wm = w >> 1, wn = w & 1;
    const int m0 = blockIdx.x * 64, n0 = blockIdx.y * 64, z = blockIdx.z;
    const float* __restrict__ W    = (z == 0) ? Wq : (z == 1) ? Wk : Wv;
    const float* __restrict__ bias = (z == 0) ? bq : (z == 1) ? bk : bv;

    __shared__ ushort_t Ah[2][64][40];
    __shared__ ushort_t Al[2][64][40];
    __shared__ ushort_t Bh[2][64][40];
    __shared__ ushort_t Bl[2][64][40];

    const int ar = t >> 2, ac = (t & 3) * 8;
    const int bn = t & 63, bk8 = (t >> 6) * 8;

    const float* agp = x + (size_t)(m0 + ar) * EMBED + ac;
    const float* bgp = W + (size_t)bk8 * EMBED + n0 + bn;

    float areg[8], breg[8];
    *(float4*)&areg[0] = *(const float4*)(agp);
    *(float4*)&areg[4] = *(const float4*)(agp + 4);
    #pragma unroll
    for (int j = 0; j < 8; ++j) breg[j] = bgp[(size_t)j * EMBED];

    f32x4 acc[2][2];
    #pragma unroll
    for (int mt = 0; mt < 2; ++mt)
        #pragma unroll
        for (int nt = 0; nt < 2; ++nt)
            acc[mt][nt] = (f32x4){0.f, 0.f, 0.f, 0.f};

    for (int ks = 0; ks < 8; ++ks) {
        const int p = ks & 1;
        {
            bf16x8 h, l;
            cvt8_hilo(areg, h, l);
            v8cast ch; ch.v = h; *(uint4*)&Ah[p][ar][ac] = ch.u;
            v8cast cl; cl.v = l; *(uint4*)&Al[p][ar][ac] = cl.u;
        }
        {
            bf16x8 h, l;
            cvt8_hilo(breg, h, l);
            v8cast ch; ch.v = h; *(uint4*)&Bh[p][bn][bk8] = ch.u;
            v8cast cl; cl.v = l; *(uint4*)&Bl[p][bn][bk8] = cl.u;
        }
        __syncthreads();
        if (ks < 7) {
            const int k1 = (ks + 1) * 32;
            *(float4*)&areg[0] = *(const float4*)(agp + k1);
            *(float4*)&areg[4] = *(const float4*)(agp + k1 + 4);
            const float* bg = bgp + (size_t)k1 * EMBED;
            #pragma unroll
            for (int j = 0; j < 8; ++j) breg[j] = bg[(size_t)j * EMBED];
        }
        bf16x8 ah[2], al_[2], bh[2], bl_[2];
        #pragma unroll
        for (int mt = 0; mt < 2; ++mt) {
            ah[mt]  = *(const bf16x8*)&Ah[p][wm * 32 + mt * 16 + li][quad * 8];
            al_[mt] = *(const bf16x8*)&Al[p][wm * 32 + mt * 16 + li][quad * 8];
        }
        #pragma unroll
        for (int nt = 0; nt < 2; ++nt) {
            bh[nt]  = *(const bf16x8*)&Bh[p][wn * 32 + nt * 16 + li][quad * 8];
            bl_[nt] = *(const bf16x8*)&Bl[p][wn * 32 + nt * 16 + li][quad * 8];
        }
        #pragma unroll
        for (int mt = 0; mt < 2; ++mt)
            #pragma unroll
            for (int nt = 0; nt < 2; ++nt) {
                acc[mt][nt] = __builtin_amdgcn_mfma_f32_16x16x32_bf16(ah[mt],  bh[nt],  acc[mt][nt], 0, 0, 0);
                acc[mt][nt] = __builtin_amdgcn_mfma_f32_16x16x32_bf16(al_[mt], bh[nt],  acc[mt][nt], 0, 0, 0);
                acc[mt][nt] = __builtin_amdgcn_mfma_f32_16x16x32_bf16(ah[mt],  bl_[nt], acc[mt][nt], 0, 0, 0);
            }
    }

    const int b = m0 / SEQ;
    const int sbase = m0 - b * SEQ + wm * 32;

    if (z <= 1) {
        ushort_t* __restrict__ dst = z ? ko : qo;
        #pragma unroll
        for (int nt = 0; nt < 2; ++nt) {
            const int gcol = n0 + wn * 32 + nt * 16 + li;
            const int h = gcol >> 5, p = gcol & 31;
            const float bb = bias[gcol];
            ushort_t* base = dst + ((size_t)(b * HEADS + h) * SEQ) * PDIM + p;
            #pragma unroll
            for (int mt = 0; mt < 2; ++mt)
                #pragma unroll
                for (int r = 0; r < 4; ++r) {
                    const int s = sbase + mt * 16 + quad * 4 + r;
                    base[(size_t)s * PDIM] = f2bf_rne(acc[mt][nt][r] + bb);
                }
        }
    } else {
        #pragma unroll
        for (int nt = 0; nt < 2; ++nt) {
            const int gcol = n0 + wn * 32 + nt * 16 + li;
            const int h = gcol >> 5, p = gcol & 31;
            const float bb = bias[gcol];
            ushort_t* base = vt + ((size_t)(b * HEADS + h) * PDIM + p) * SEQ;
            #pragma unroll
            for (int mt = 0; mt < 2; ++mt) {
                const int s0 = sbase + mt * 16 + quad * 4;
                ushort4 wv4;
                wv4.x = f2bf_rne(acc[mt][nt][0] + bb);
                wv4.y = f2bf_rne(acc[mt][nt][1] + bb);
                wv4.z = f2bf_rne(acc[mt][nt][2] + bb);
                wv4.w = f2bf_rne(acc[mt][nt][3] + bb);
                *(ushort4*)&base[s0] = wv4;
            }
        }
    }
}

// ---------------------------------------------------------------------------
// Kernel 2: flash attention, 8 waves x 64 q-rows, KV-RANGE split.
// grid 432 x 512.  Wave (qg,half): qg=w>>1 owns 16 q-rows, half=w&1 owns a
// contiguous half of the key range (half0: tiles 0..13, half1: 14..26, 64-key
// tiles).  Serial chain per block: 14 iterations of half-work (was 13.5 of
// full).  LDS 56 KB (Om/Ml alias Ps/Ks across a barrier) -> 2 blocks/CU ->
// 4 waves/SIMD (was 1.7).  Exact flash combine per wave pair at the end.
// Output bf16 [b][s][h][p].
// ---------------------------------------------------------------------------
__global__ __launch_bounds__(512, 4) void attn_kernel(
    const ushort_t* __restrict__ q, const ushort_t* __restrict__ k,
    const ushort_t* __restrict__ vt, ushort_t* __restrict__ aob)
{
    const int t    = threadIdx.x;
    const int lane = t & 63;
    const int w    = t >> 6;
    const int li   = lane & 15;
    const int quad = lane >> 4;
    const int qg   = w >> 1, half = w & 1;
    // XCD-aware block decode (perf heuristic only)
    const int bid = blockIdx.x;
    const int g = bid & 7, j = bid >> 3;
    const int bh = g * 2 + (j >= 27 ? 1 : 0);
    const int qt = (j >= 27) ? (j - 27) : j;
    const int b  = bh >> 3, h = bh & 7;
    const int q0 = qt * 64 + qg * 16;

    const ushort_t* __restrict__ qb = q  + (size_t)bh * SEQ * PDIM;
    const ushort_t* __restrict__ kb = k  + (size_t)bh * SEQ * PDIM;
    const ushort_t* __restrict__ vb = vt + (size_t)bh * PDIM * SEQ;

    // LDS layout (raw buffer, 57344 B total):
    //   [0,20480)      Ks[2][2][64][40]   (Ml aliases first 1 KB after loop)
    //   [20480,38912)  Vs[2][2][32][72]
    //   [38912,57344)  Ps[8][16][72]      (Om[8][16][33] f32 aliases after loop)
    __shared__ __align__(16) char SMRAW[57344];
    ushort_t (*Ks)[2][64][40] = reinterpret_cast<ushort_t (*)[2][64][40]>(SMRAW);
    ushort_t (*Vs)[2][32][72] = reinterpret_cast<ushort_t (*)[2][32][72]>(SMRAW + 20480);
    ushort_t (*Ps)[16][72]    = reinterpret_cast<ushort_t (*)[16][72]>(SMRAW + 38912);
    float    (*Om)[16][33]    = reinterpret_cast<float (*)[16][33]>(SMRAW + 38912);
    float    (*Ml)[2][16]     = reinterpret_cast<float (*)[2][16]>(SMRAW);

    const bf16x8 qfrag = *(const bf16x8*)(qb + (size_t)(q0 + li) * PDIM + quad * 8);

    // staging: threads 0-255 stage half0's tile, 256-511 stage half1's.
    const int ts = t & 255, hstage = t >> 8;
    const int krow = ts >> 2, kc = (ts & 3) * 8;
    const int vrow = ts >> 3, vk = (ts & 7) * 8;
    const int tb = hstage ? 896 : 0;           // key base row of this half

    f32x4 o0 = {0.f, 0.f, 0.f, 0.f};
    f32x4 o1 = {0.f, 0.f, 0.f, 0.f};
    float m_run = -__builtin_inff(), l_run = 0.f;

    uint4 kreg = *(const uint4*)(kb + (size_t)(tb + krow) * PDIM + kc);
    uint4 vreg = *(const uint4*)(vb + (size_t)vrow * SEQ + tb + vk);

    const int myn = half ? 13 : 14;            // compute tiles for this wave

    for (int it = 0; it < 14; ++it) {
        const int p = it & 1;
        *(uint4*)&Ks[p][hstage][krow][kc] = kreg;
        *(uint4*)&Vs[p][hstage][vrow][vk] = vreg;
        __syncthreads();
        if (it + 1 < 14) {
            const int nt_ = it + 1;
            const int t1 = hstage ? (14 + nt_ > 26 ? 26 : 14 + nt_) : nt_;
            kreg = *(const uint4*)(kb + (size_t)(t1 * 64 + krow) * PDIM + kc);
            vreg = *(const uint4*)(vb + (size_t)vrow * SEQ + t1 * 64 + vk);
        }

        if (it < myn) {
            // ---- S^T = K * Q^T ----
            const f32x4 zero = {0.f, 0.f, 0.f, 0.f};
            f32x4 st[4];
            #pragma unroll
            for (int jt = 0; jt < 4; ++jt) {
                const bf16x8 kf = *(const bf16x8*)&Ks[p][half][jt * 16 + li][quad * 8];
                st[jt] = __builtin_amdgcn_mfma_f32_16x16x32_bf16(kf, qfrag, zero, 0, 0, 0);
            }

            // ---- online softmax ----
            float tm = st[0][0];
            #pragma unroll
            for (int jt = 0; jt < 4; ++jt)
                #pragma unroll
                for (int r = 0; r < 4; ++r) tm = fmaxf(tm, st[jt][r]);
            tm = fmaxf(tm, __shfl_xor(tm, 16));
            tm = fmaxf(tm, __shfl_xor(tm, 32));
            const float mnew  = fmaxf(m_run, tm);
            const float negml = -(mnew * LOG2E);

            float ps = 0.f;
            #pragma unroll
            for (int jt = 0; jt < 4; ++jt) {
                const float p0 = __builtin_amdgcn_exp2f(fmaf(st[jt][0], LOG2E, negml));
                const float p1 = __builtin_amdgcn_exp2f(fmaf(st[jt][1], LOG2E, negml));
                const float p2 = __builtin_amdgcn_exp2f(fmaf(st[jt][2], LOG2E, negml));
                const float p3 = __builtin_amdgcn_exp2f(fmaf(st[jt][3], LOG2E, negml));
                ps += (p0 + p1) + (p2 + p3);
                uint2 pw;
                pw.x = __builtin_amdgcn_perm(__float_as_uint(p1) + 0x8000u,
                                             __float_as_uint(p0) + 0x8000u, 0x07060302u);
                pw.y = __builtin_amdgcn_perm(__float_as_uint(p3) + 0x8000u,
                                             __float_as_uint(p2) + 0x8000u, 0x07060302u);
                *(uint2*)&Ps[w][li][16 * jt + 4 * quad] = pw;
            }
            ps += __shfl_xor(ps, 16);
            ps += __shfl_xor(ps, 32);

            const float alpha = __builtin_amdgcn_exp2f(fmaf(m_run, LOG2E, negml));
            l_run = fmaf(l_run, alpha, ps);
            m_run = mnew;

            float af[4];
            #pragma unroll
            for (int r = 0; r < 4; ++r) af[r] = __shfl(alpha, 4 * quad + r);
            #pragma unroll
            for (int r = 0; r < 4; ++r) { o0[r] *= af[r]; o1[r] *= af[r]; }

            // ---- O += P * V ----
            const bf16x8 pa0 = *(const bf16x8*)&Ps[w][li][8 * quad];
            const bf16x8 pa1 = *(const bf16x8*)&Ps[w][li][32 + 8 * quad];
            const bf16x8 vf00 = *(const bf16x8*)&Vs[p][half][li][quad * 8];
            const bf16x8 vf01 = *(const bf16x8*)&Vs[p][half][16 + li][quad * 8];
            const bf16x8 vf10 = *(const bf16x8*)&Vs[p][half][li][32 + quad * 8];
            const bf16x8 vf11 = *(const bf16x8*)&Vs[p][half][16 + li][32 + quad * 8];
            o0 = __builtin_amdgcn_mfma_f32_16x16x32_bf16(pa0, vf00, o0, 0, 0, 0);
            o0 = __builtin_amdgcn_mfma_f32_16x16x32_bf16(pa1, vf10, o0, 0, 0, 0);
            o1 = __builtin_amdgcn_mfma_f32_16x16x32_bf16(pa0, vf01, o1, 0, 0, 0);
            o1 = __builtin_amdgcn_mfma_f32_16x16x32_bf16(pa1, vf11, o1, 0, 0, 0);
        }
    }

    // ---- publish partials (barrier first: Om/Ml alias Ps/Ks) ----
    __syncthreads();
    #pragma unroll
    for (int r = 0; r < 4; ++r) {
        Om[w][4 * quad + r][li]      = o0[r];
        Om[w][4 * quad + r][16 + li] = o1[r];
    }
    if (quad == 0) { Ml[w][0][li] = m_run; Ml[w][1][li] = l_run; }
    __syncthreads();

    // ---- exact flash combine across the wave pair; each wave writes 16 cols
    const int wa = qg * 2, wb = wa + 1;
    const float ma = Ml[wa][0][li], mb = Ml[wb][0][li];
    const float mC = fmaxf(ma, mb);
    const float sa = __builtin_amdgcn_exp2f((ma - mC) * LOG2E);
    const float sb = __builtin_amdgcn_exp2f((mb - mC) * LOG2E);
    const float lC = Ml[wa][1][li] * sa + Ml[wb][1][li] * sb;
    const float inv = 1.0f / lC;
    const float fa = sa * inv, fb = sb * inv;
    const int c = half * 16 + li;
    #pragma unroll
    for (int r = 0; r < 4; ++r) {
        const int qq = 4 * quad + r;
        const float aq  = __shfl(fa, qq);
        const float bq_ = __shfl(fb, qq);
        const float val = Om[wa][qq][c] * aq + Om[wb][qq][c] * bq_;
        const int s = q0 + qq;
        aob[((size_t)(b * SEQ + s)) * EMBED + h * PDIM + c] = f2bf_rne(val);
    }
}

// ---------------------------------------------------------------------------
// Kernel 3: output projection.  Block = 256 thr (4 waves), tile 128Mx16N;
// Wo[256][n0..n0+16] converted hi-bf16 ONCE per block into LDS (27x
// redundancy, was 108x; coalesced), then a barrier-free k-loop:
// 2 global b128 (A bf16) + 1 LDS b128 + 2 MFMA per k-step per wave.
// grid (27, 16) x 256.  B-fragment values bit-identical to R4/R5.
// ---------------------------------------------------------------------------
__global__ __launch_bounds__(256) void out_gemm_kernel(
    const ushort_t* __restrict__ a, const float* __restrict__ Wo,
    const float* __restrict__ bo, float* __restrict__ out)
{
    const int t = threadIdx.x;
    const int lane = t & 63, li = lane & 15, quad = lane >> 4;
    const int w = t >> 6;
    const int m0 = blockIdx.x * 128 + w * 32, n0 = blockIdx.y * 16;

    __shared__ ushort_t Bh[16][260];   // row stride 520 B -> 2-way max aliasing

    // one-time cooperative stage: thread t -> col n, k-chunk kc (16 elems)
    {
        const int n = t & 15, kc = (t >> 4) * 16;
        const float* wp = Wo + (size_t)kc * EMBED + n0 + n;
        uint4 q0v, q1v;
        uint_t* b0 = (uint_t*)&q0v; uint_t* b1 = (uint_t*)&q1v;
        #pragma unroll
        for (int j = 0; j < 4; ++j) {
            const uint_t u0 = __float_as_uint(wp[(size_t)(2 * j) * EMBED])     + 0x8000u;
            const uint_t u1 = __float_as_uint(wp[(size_t)(2 * j + 1) * EMBED]) + 0x8000u;
            b0[j] = __builtin_amdgcn_perm(u1, u0, 0x07060302u);
            const uint_t u2 = __float_as_uint(wp[(size_t)(8 + 2 * j) * EMBED])     + 0x8000u;
            const uint_t u3 = __float_as_uint(wp[(size_t)(8 + 2 * j + 1) * EMBED]) + 0x8000u;
            b1[j] = __builtin_amdgcn_perm(u3, u2, 0x07060302u);
        }
        *(uint4*)&Bh[n][kc]     = q0v;
        *(uint4*)&Bh[n][kc + 8] = q1v;
    }
    __syncthreads();

    const ushort_t* aph = a + (size_t)(m0 + li) * EMBED + quad * 8;

    f32x4 acc[2];
    #pragma unroll
    for (int mt = 0; mt < 2; ++mt) acc[mt] = (f32x4){0.f, 0.f, 0.f, 0.f};

    #pragma unroll 2
    for (int k0 = 0; k0 < EMBED; k0 += 32) {
        bf16x8 ah[2];
        #pragma unroll
        for (int mt = 0; mt < 2; ++mt)
            ah[mt] = *(const bf16x8*)(aph + (size_t)mt * 16 * EMBED + k0);
        const bf16x8 bf = *(const bf16x8*)&Bh[li][k0 + quad * 8];
        #pragma unroll
        for (int mt = 0; mt < 2; ++mt)
            acc[mt] = __builtin_amdgcn_mfma_f32_16x16x32_bf16(ah[mt], bf, acc[mt], 0, 0, 0);
    }

    const float bb = bo[n0 + li];
    #pragma unroll
    for (int mt = 0; mt < 2; ++mt)
        #pragma unroll
        for (int r = 0; r < 4; ++r) {
            const int row = m0 + mt * 16 + quad * 4 + r;
            out[(size_t)row * EMBED + n0 + li] = acc[mt][r] + bb;
        }
}

// ---------------------------------------------------------------------------
extern "C" void kernel_launch(void* const* d_in, const int* in_sizes, int n_in,
                              void* d_out, int out_size, void* d_ws, size_t ws_size,
                              hipStream_t stream)
{
    const float* x  = (const float*)d_in[0];
    const float* Wq = (const float*)d_in[1];
    const float* bq = (const float*)d_in[2];
    const float* Wk = (const float*)d_in[3];
    const float* bk = (const float*)d_in[4];
    const float* Wv = (const float*)d_in[5];
    const float* bv = (const float*)d_in[6];
    const float* Wo = (const float*)d_in[7];
    const float* bo = (const float*)d_in[8];
    float* out = (float*)d_out;

    ushort_t* ws  = (ushort_t*)d_ws;
    ushort_t* qb  = ws;                      // [b][h][s][p] bf16
    ushort_t* kb  = qb + (size_t)NE;
    ushort_t* vt  = kb + (size_t)NE;         // [b][h][p][s] bf16
    ushort_t* aob = vt + (size_t)NE;         // [b][s][h][p] bf16

    qkv_gemm_kernel<<<dim3(NTOK / 64, EMBED / 64, 3), 256, 0, stream>>>(
        x, Wq, bq, Wk, bk, Wv, bv, qb, kb, vt);
    attn_kernel<<<dim3(432), 512, 0, stream>>>(qb, kb, vt, aob);
    out_gemm_kernel<<<dim3(NTOK / 128, 16), 256, 0, stream>>>(aob, Wo, bo, out);
}